// Round 1
// baseline (1266.341 us; speedup 1.0000x reference)
//
#include <hip/hip_runtime.h>
#include <cstddef>
#include <cstdint>

#define IDIV(a, b) (((a) + (b) - 1) / (b))

// ---------------------------------------------------------------- utilities

__global__ void k_zero_i32(int* __restrict__ p, int n) {
  int i = blockIdx.x * blockDim.x + threadIdx.x;
  if (i < n) p[i] = 0;
}

__global__ void k_zero_f32(float* __restrict__ p, int n) {
  int i = blockIdx.x * blockDim.x + threadIdx.x;
  if (i < n) p[i] = 0.f;
}

// ---------------------------------------------------------------- CSR build

__global__ void k_count(const int* __restrict__ dst, int E, int* __restrict__ cnt) {
  int i = blockIdx.x * blockDim.x + threadIdx.x;
  if (i < E) atomicAdd(&cnt[dst[i]], 1);
}

__global__ void k_scan_partial(const int* __restrict__ cnt, int n, int* __restrict__ part) {
  __shared__ int sm[256];
  const int t = threadIdx.x;
  const int i = blockIdx.x * 256 + t;
  sm[t] = (i < n) ? cnt[i] : 0;
  __syncthreads();
  for (int off = 128; off > 0; off >>= 1) {
    if (t < off) sm[t] += sm[t + off];
    __syncthreads();
  }
  if (t == 0) part[blockIdx.x] = sm[0];
}

__global__ void k_scan_offsets(int* __restrict__ part, int nb) {
  __shared__ int sm[256];
  const int t = threadIdx.x;
  if (t < nb) sm[t] = part[t];
  __syncthreads();
  if (t == 0) {
    int run = 0;
    for (int i = 0; i < nb; ++i) { int v = sm[i]; sm[i] = run; run += v; }
  }
  __syncthreads();
  if (t < nb) part[t] = sm[t];
}

__global__ void k_scan_final(const int* __restrict__ cnt, int n, const int* __restrict__ part,
                             int* __restrict__ row_ptr) {
  __shared__ int sm[256];
  const int t = threadIdx.x;
  const int i = blockIdx.x * 256 + t;
  const int v = (i < n) ? cnt[i] : 0;
  sm[t] = v;
  __syncthreads();
  for (int off = 1; off < 256; off <<= 1) {
    int x = (t >= off) ? sm[t - off] : 0;
    __syncthreads();
    sm[t] += x;
    __syncthreads();
  }
  if (i < n) row_ptr[i] = part[blockIdx.x] + sm[t] - v;  // exclusive scan
}

__global__ void k_cursor_dis(const int* __restrict__ row_ptr, const int* __restrict__ cnt,
                             int* __restrict__ cursor, float* __restrict__ dis,
                             int* __restrict__ row_ptr_end, int n, int E) {
  int i = blockIdx.x * blockDim.x + threadIdx.x;
  if (i == 0) *row_ptr_end = E;
  if (i < n) {
    cursor[i] = row_ptr[i];
    dis[i] = rsqrtf((float)cnt[i] + 1.0f);
  }
}

__global__ void k_scatter(const int* __restrict__ src, const int* __restrict__ dst, int E,
                          int* __restrict__ cursor, int* __restrict__ col) {
  int i = blockIdx.x * blockDim.x + threadIdx.x;
  if (i < E) {
    int d = dst[i];
    int pos = atomicAdd(&cursor[d], 1);
    col[pos] = src[i];
  }
}

// ---------------------------------------------------------------- GEMM
// C[N,O] = op(A)[N,K] @ W[K,O] (+ bias)
// op(A) = PRO ? lrelu(A*scale + shift) : A   (scale/shift per K-column, packed in ss[0..K),ss[K..2K))

template <int K, int O, bool PRO, bool BIAS>
__launch_bounds__(256)
__global__ void k_gemm(const float* __restrict__ A, const float* __restrict__ W,
                       const float* __restrict__ bias, const float* __restrict__ ss,
                       float* __restrict__ C, int N) {
  __shared__ float As[64][36];  // stride 36 floats = 144B: float4-aligned, bank-spread
  __shared__ float Bs[32][64];
  const int bm = blockIdx.x * 64;
  const int bo = blockIdx.y * 64;
  const int t = threadIdx.x;
  const int tx = t & 15, ty = t >> 4;
  float acc[4][4] = {{0.f}};

  for (int k0 = 0; k0 < K; k0 += 32) {
    // ---- stage A tile (64 rows x 32 k) with fused BN+lrelu prologue
    {
      const int r = t >> 3;        // 0..31
      const int c = (t & 7) * 4;   // 0..28
#pragma unroll
      for (int rr = 0; rr < 64; rr += 32) {
        const int row = bm + rr + r;
        float4 v = make_float4(0.f, 0.f, 0.f, 0.f);
        if (row < N) v = *reinterpret_cast<const float4*>(&A[(size_t)row * K + k0 + c]);
        if (PRO) {
          const float4 sc = *reinterpret_cast<const float4*>(&ss[k0 + c]);
          const float4 sh = *reinterpret_cast<const float4*>(&ss[K + k0 + c]);
          v.x = v.x * sc.x + sh.x; v.x = v.x > 0.f ? v.x : 0.01f * v.x;
          v.y = v.y * sc.y + sh.y; v.y = v.y > 0.f ? v.y : 0.01f * v.y;
          v.z = v.z * sc.z + sh.z; v.z = v.z > 0.f ? v.z : 0.01f * v.z;
          v.w = v.w * sc.w + sh.w; v.w = v.w > 0.f ? v.w : 0.01f * v.w;
        }
        *reinterpret_cast<float4*>(&As[rr + r][c]) = v;
      }
    }
    // ---- stage W tile (32 k x 64 cols)
    {
      const int r = t >> 4;        // 0..15
      const int c = (t & 15) * 4;  // 0..60
#pragma unroll
      for (int rr = 0; rr < 32; rr += 16) {
        *reinterpret_cast<float4*>(&Bs[rr + r][c]) =
            *reinterpret_cast<const float4*>(&W[(size_t)(k0 + rr + r) * O + bo + c]);
      }
    }
    __syncthreads();
#pragma unroll
    for (int kk = 0; kk < 32; ++kk) {
      const float a0 = As[ty * 4 + 0][kk];
      const float a1 = As[ty * 4 + 1][kk];
      const float a2 = As[ty * 4 + 2][kk];
      const float a3 = As[ty * 4 + 3][kk];
      const float4 b = *reinterpret_cast<const float4*>(&Bs[kk][tx * 4]);
      acc[0][0] += a0 * b.x; acc[0][1] += a0 * b.y; acc[0][2] += a0 * b.z; acc[0][3] += a0 * b.w;
      acc[1][0] += a1 * b.x; acc[1][1] += a1 * b.y; acc[1][2] += a1 * b.z; acc[1][3] += a1 * b.w;
      acc[2][0] += a2 * b.x; acc[2][1] += a2 * b.y; acc[2][2] += a2 * b.z; acc[2][3] += a2 * b.w;
      acc[3][0] += a3 * b.x; acc[3][1] += a3 * b.y; acc[3][2] += a3 * b.z; acc[3][3] += a3 * b.w;
    }
    __syncthreads();
  }

  float4 bv = make_float4(0.f, 0.f, 0.f, 0.f);
  if (BIAS) bv = *reinterpret_cast<const float4*>(&bias[bo + tx * 4]);
#pragma unroll
  for (int i = 0; i < 4; ++i) {
    const int row = bm + ty * 4 + i;
    if (row < N) {
      float4 o;
      o.x = acc[i][0] + bv.x;
      o.y = acc[i][1] + bv.y;
      o.z = acc[i][2] + bv.z;
      o.w = acc[i][3] + bv.w;
      *reinterpret_cast<float4*>(&C[(size_t)row * O + bo + tx * 4]) = o;
    }
  }
}

// ---------------------------------------------------------------- BN column stats

template <int H>
__global__ void k_colstats(const float* __restrict__ X, int n, float* __restrict__ sums) {
  constexpr int NSUB = 256 / H;
  const int t = threadIdx.x;
  const int c = t % H;
  const int sub = t / H;
  const int r0 = blockIdx.x * 256;
  float s = 0.f, s2 = 0.f;
  const int rend = (r0 + 256 < n) ? r0 + 256 : n;
  for (int r = r0 + sub; r < rend; r += NSUB) {
    const float v = X[(size_t)r * H + c];
    s += v;
    s2 += v * v;
  }
  atomicAdd(&sums[c], s);
  atomicAdd(&sums[H + c], s2);
}

__global__ void k_bnfin(const float* __restrict__ sums, const float* __restrict__ g,
                        const float* __restrict__ b, float* __restrict__ ss, int H, float invN) {
  const int c = threadIdx.x;
  if (c < H) {
    const float mean = sums[c] * invN;
    float var = sums[H + c] * invN - mean * mean;
    var = var < 0.f ? 0.f : var;
    const float sc = g[c] * rsqrtf(var + 1e-5f);
    ss[c] = sc;
    ss[H + c] = b[c] - mean * sc;
  }
}

// ---------------------------------------------------------------- GCN aggregation
// out[d] = sum_{e:(s->d)} Hin[s]*dis[s]*dis[d] + Hin[d]*dis[d]^2 + bias

template <int H>
__launch_bounds__(256)
__global__ void k_agg(const float* __restrict__ Hin, const int* __restrict__ row_ptr,
                      const int* __restrict__ col, const float* __restrict__ dis,
                      const float* __restrict__ bias, float* __restrict__ out, int n) {
  constexpr int V = H / 64;
  const int lane = threadIdx.x & 63;
  const int node = blockIdx.x * 4 + (threadIdx.x >> 6);
  if (node >= n) return;
  const int beg = row_ptr[node];
  const int end = row_ptr[node + 1];
  const float dd = dis[node];
  float acc[V];
#pragma unroll
  for (int j = 0; j < V; ++j) acc[j] = 0.f;
  for (int e = beg; e < end; ++e) {
    const int s = col[e];
    const float w = dis[s] * dd;
    const float* hp = &Hin[(size_t)s * H + lane * V];
    if constexpr (V == 4) {
      const float4 v = *reinterpret_cast<const float4*>(hp);
      acc[0] += v.x * w; acc[1] += v.y * w; acc[2] += v.z * w; acc[3] += v.w * w;
    } else if constexpr (V == 2) {
      const float2 v = *reinterpret_cast<const float2*>(hp);
      acc[0] += v.x * w; acc[1] += v.y * w;
    } else {
      acc[0] += hp[0] * w;
    }
  }
  const float sw = dd * dd;
  const float* hs = &Hin[(size_t)node * H + lane * V];
#pragma unroll
  for (int j = 0; j < V; ++j) acc[j] += hs[j] * sw;
  float* op = &out[(size_t)node * H + lane * V];
#pragma unroll
  for (int j = 0; j < V; ++j) op[j] = acc[j] + bias[lane * V + j];
}

// ---------------------------------------------------------------- residual combine
// xin = (BN(xin) + h) * 2^-0.5 + xin   (elementwise, in place on xin)

template <int H>
__global__ void k_combine(float* __restrict__ xin, const float* __restrict__ h,
                          const float* __restrict__ ss, int total) {
  const float cinv = 0.70710678118654752f;
  int i = blockIdx.x * blockDim.x + threadIdx.x;
  if (i < total) {
    const int c = i & (H - 1);
    const float v = xin[i];
    const float bn = v * ss[c] + ss[H + c];
    xin[i] = (bn + h[i]) * cinv + v;
  }
}

// ---------------------------------------------------------------- launch

extern "C" void kernel_launch(void* const* d_in, const int* in_sizes, int n_in,
                              void* d_out, int out_size, void* d_ws, size_t ws_size,
                              hipStream_t stream) {
  const int N = in_sizes[0] / 128;
  const int E = in_sizes[1] / 2;

  const float* x_vert = (const float*)d_in[0];
  const int* src = (const int*)d_in[1];
  const int* dst = src + E;
  const float* g1_lin_W = (const float*)d_in[2];
  const float* g1_lin_b = (const float*)d_in[3];
  const float* g1_c1_W = (const float*)d_in[4];
  const float* g1_c1_b = (const float*)d_in[5];
  const float* g1_c2_W = (const float*)d_in[6];
  const float* g1_c2_b = (const float*)d_in[7];
  const float* g1_n1_g = (const float*)d_in[8];
  const float* g1_n1_b = (const float*)d_in[9];
  const float* g1_n2_g = (const float*)d_in[10];
  const float* g1_n2_b = (const float*)d_in[11];
  const float* g2_lin_W = (const float*)d_in[12];
  const float* g2_lin_b = (const float*)d_in[13];
  const float* g2_c1_W = (const float*)d_in[14];
  const float* g2_c1_b = (const float*)d_in[15];
  const float* g2_c2_W = (const float*)d_in[16];
  const float* g2_c2_b = (const float*)d_in[17];
  const float* g2_n1_g = (const float*)d_in[18];
  const float* g2_n1_b = (const float*)d_in[19];
  const float* g2_n2_g = (const float*)d_in[20];
  const float* g2_n2_b = (const float*)d_in[21];
  const float* out_W = (const float*)d_in[22];
  const float* out_b = (const float*)d_in[23];
  const float* n1_g = (const float*)d_in[24];
  const float* n1_b = (const float*)d_in[25];
  const float* l1_W = (const float*)d_in[26];
  const float* l1_b = (const float*)d_in[27];
  const float* n2_g = (const float*)d_in[28];
  const float* n2_b = (const float*)d_in[29];
  const float* l2_W = (const float*)d_in[30];
  const float* l2_b = (const float*)d_in[31];

  float* out = (float*)d_out;

  // ---- workspace carve-up
  size_t off = 0;
  auto alloc = [&](size_t bytes) -> void* {
    void* p = (char*)d_ws + off;
    off += (bytes + 255) & ~(size_t)255;
    return p;
  };
  float* B1 = (float*)alloc((size_t)N * 256 * 4);
  float* B2 = (float*)alloc((size_t)N * 256 * 4);
  float* B3 = (float*)alloc((size_t)N * 256 * 4);
  int* cnt = (int*)alloc((size_t)N * 4);
  int* row_ptr = (int*)alloc((size_t)(N + 1) * 4);
  int* cursor = (int*)alloc((size_t)N * 4);
  int* col = (int*)alloc((size_t)E * 4);
  int* part = (int*)alloc(1024 * 4);
  float* dis = (float*)alloc((size_t)N * 4);
  float* sums = (float*)alloc(512 * 4);
  float* ssA = (float*)alloc(512 * 4);
  float* ssB = (float*)alloc(512 * 4);
  (void)ws_size;
  (void)n_in;
  (void)out_size;

  const int NB = IDIV(N, 256);
  const float invN = 1.0f / (float)N;

  // ---- CSR build (by destination) + degrees
  k_zero_i32<<<NB, 256, 0, stream>>>(cnt, N);
  k_count<<<IDIV(E, 256), 256, 0, stream>>>(dst, E, cnt);
  k_scan_partial<<<NB, 256, 0, stream>>>(cnt, N, part);
  k_scan_offsets<<<1, 256, 0, stream>>>(part, NB);
  k_scan_final<<<NB, 256, 0, stream>>>(cnt, N, part, row_ptr);
  k_cursor_dis<<<NB, 256, 0, stream>>>(row_ptr, cnt, cursor, dis, row_ptr + N, N, E);
  k_scatter<<<IDIV(E, 256), 256, 0, stream>>>(src, dst, E, cursor, col);

  const dim3 g256(IDIV(N, 64), 4), g128(IDIV(N, 64), 2), g64(IDIV(N, 64), 1);

  // ================= block 1 (in 128, hid 256) =================
  // x_in = x @ lin_W + lin_b -> B1
  k_gemm<128, 256, false, true><<<g256, 256, 0, stream>>>(x_vert, g1_lin_W, g1_lin_b, nullptr, B1, N);
  // BN1 stats -> ssA
  k_zero_f32<<<2, 256, 0, stream>>>(sums, 512);
  k_colstats<256><<<NB, 256, 0, stream>>>(B1, N, sums);
  k_bnfin<<<1, 256, 0, stream>>>(sums, g1_n1_g, g1_n1_b, ssA, 256, invN);
  // h1 = lrelu(BN(B1)) @ c1_W -> B2 ; aggregate -> B3 (+c1_b)
  k_gemm<256, 256, true, false><<<g256, 256, 0, stream>>>(B1, g1_c1_W, nullptr, ssA, B2, N);
  k_agg<256><<<IDIV(N, 4), 256, 0, stream>>>(B2, row_ptr, col, dis, g1_c1_b, B3, N);
  // BN2 stats -> ssB
  k_zero_f32<<<2, 256, 0, stream>>>(sums, 512);
  k_colstats<256><<<NB, 256, 0, stream>>>(B3, N, sums);
  k_bnfin<<<1, 256, 0, stream>>>(sums, g1_n2_g, g1_n2_b, ssB, 256, invN);
  // h2 = lrelu(BN(B3)) @ c2_W -> B2 ; aggregate -> B3 (+c2_b)
  k_gemm<256, 256, true, false><<<g256, 256, 0, stream>>>(B3, g1_c2_W, nullptr, ssB, B2, N);
  k_agg<256><<<IDIV(N, 4), 256, 0, stream>>>(B2, row_ptr, col, dis, g1_c2_b, B3, N);
  // B1 = (BN1(B1) + B3)*c + B1
  k_combine<256><<<IDIV(N * 256, 256), 256, 0, stream>>>(B1, B3, ssA, N * 256);

  // ================= block 2 (in 256, hid 128) =================
  k_gemm<256, 128, false, true><<<g128, 256, 0, stream>>>(B1, g2_lin_W, g2_lin_b, nullptr, B2, N);
  k_zero_f32<<<1, 256, 0, stream>>>(sums, 256);
  k_colstats<128><<<NB, 256, 0, stream>>>(B2, N, sums);
  k_bnfin<<<1, 256, 0, stream>>>(sums, g2_n1_g, g2_n1_b, ssA, 128, invN);
  k_gemm<128, 128, true, false><<<g128, 256, 0, stream>>>(B2, g2_c1_W, nullptr, ssA, B3, N);
  k_agg<128><<<IDIV(N, 4), 256, 0, stream>>>(B3, row_ptr, col, dis, g2_c1_b, B1, N);
  k_zero_f32<<<1, 256, 0, stream>>>(sums, 256);
  k_colstats<128><<<NB, 256, 0, stream>>>(B1, N, sums);
  k_bnfin<<<1, 256, 0, stream>>>(sums, g2_n2_g, g2_n2_b, ssB, 128, invN);
  k_gemm<128, 128, true, false><<<g128, 256, 0, stream>>>(B1, g2_c2_W, nullptr, ssB, B3, N);
  k_agg<128><<<IDIV(N, 4), 256, 0, stream>>>(B3, row_ptr, col, dis, g2_c2_b, B1, N);
  k_combine<128><<<IDIV(N * 128, 256), 256, 0, stream>>>(B2, B1, ssA, N * 128);

  // ================= head =================
  k_gemm<128, 128, false, true><<<g128, 256, 0, stream>>>(B2, out_W, out_b, nullptr, B1, N);
  k_zero_f32<<<1, 256, 0, stream>>>(sums, 256);
  k_colstats<128><<<NB, 256, 0, stream>>>(B1, N, sums);
  k_bnfin<<<1, 256, 0, stream>>>(sums, n1_g, n1_b, ssA, 128, invN);
  k_gemm<128, 64, true, true><<<g64, 256, 0, stream>>>(B1, l1_W, l1_b, ssA, B3, N);
  k_zero_f32<<<1, 256, 0, stream>>>(sums, 128);
  k_colstats<64><<<NB, 256, 0, stream>>>(B3, N, sums);
  k_bnfin<<<1, 256, 0, stream>>>(sums, n2_g, n2_b, ssB, 64, invN);
  k_gemm<64, 64, true, true><<<g64, 256, 0, stream>>>(B3, l2_W, l2_b, ssB, out, N);
}

// Round 2
// 1097.928 us; speedup vs baseline: 1.1534x; 1.1534x over previous
//
#include <hip/hip_runtime.h>
#include <cstddef>
#include <cstdint>

#define IDIV(a, b) (((a) + (b) - 1) / (b))

typedef __attribute__((ext_vector_type(8))) short short8;
typedef __attribute__((ext_vector_type(4))) float f32x4;

__device__ inline ushort f2bf_rne(float x) {
  uint32_t u = __builtin_bit_cast(uint32_t, x);
  u += 0x7fff + ((u >> 16) & 1);
  return (ushort)(u >> 16);
}
__device__ inline float bf2f(ushort h) {
  uint32_t u = (uint32_t)h << 16;
  return __builtin_bit_cast(float, u);
}

// ---------------------------------------------------------------- utilities

__global__ void k_zero_i32(int* __restrict__ p, int n) {
  int i = blockIdx.x * blockDim.x + threadIdx.x;
  if (i < n) p[i] = 0;
}

__global__ void k_zero_f32(float* __restrict__ p, int n) {
  int i = blockIdx.x * blockDim.x + threadIdx.x;
  if (i < n) p[i] = 0.f;
}

// ---------------------------------------------------------------- CSR build

__global__ void k_count(const int* __restrict__ dst, int E, int* __restrict__ cnt) {
  int i = blockIdx.x * blockDim.x + threadIdx.x;
  if (i < E) atomicAdd(&cnt[dst[i]], 1);
}

__global__ void k_scan_partial(const int* __restrict__ cnt, int n, int* __restrict__ part) {
  __shared__ int sm[256];
  const int t = threadIdx.x;
  const int i = blockIdx.x * 256 + t;
  sm[t] = (i < n) ? cnt[i] : 0;
  __syncthreads();
  for (int off = 128; off > 0; off >>= 1) {
    if (t < off) sm[t] += sm[t + off];
    __syncthreads();
  }
  if (t == 0) part[blockIdx.x] = sm[0];
}

__global__ void k_scan_offsets(int* __restrict__ part, int nb) {
  __shared__ int sm[256];
  const int t = threadIdx.x;
  if (t < nb) sm[t] = part[t];
  __syncthreads();
  if (t == 0) {
    int run = 0;
    for (int i = 0; i < nb; ++i) { int v = sm[i]; sm[i] = run; run += v; }
  }
  __syncthreads();
  if (t < nb) part[t] = sm[t];
}

__global__ void k_scan_final(const int* __restrict__ cnt, int n, const int* __restrict__ part,
                             int* __restrict__ row_ptr) {
  __shared__ int sm[256];
  const int t = threadIdx.x;
  const int i = blockIdx.x * 256 + t;
  const int v = (i < n) ? cnt[i] : 0;
  sm[t] = v;
  __syncthreads();
  for (int off = 1; off < 256; off <<= 1) {
    int x = (t >= off) ? sm[t - off] : 0;
    __syncthreads();
    sm[t] += x;
    __syncthreads();
  }
  if (i < n) row_ptr[i] = part[blockIdx.x] + sm[t] - v;  // exclusive scan
}

__global__ void k_cursor_dis(const int* __restrict__ row_ptr, const int* __restrict__ cnt,
                             int* __restrict__ cursor, float* __restrict__ dis,
                             int* __restrict__ row_ptr_end, int n, int E) {
  int i = blockIdx.x * blockDim.x + threadIdx.x;
  if (i == 0) *row_ptr_end = E;
  if (i < n) {
    cursor[i] = row_ptr[i];
    dis[i] = rsqrtf((float)cnt[i] + 1.0f);
  }
}

__global__ void k_scatter(const int* __restrict__ src, const int* __restrict__ dst, int E,
                          int* __restrict__ cursor, int* __restrict__ col) {
  int i = blockIdx.x * blockDim.x + threadIdx.x;
  if (i < E) {
    int d = dst[i];
    int pos = atomicAdd(&cursor[d], 1);
    col[pos] = src[i];
  }
}

// ---------------------------------------------------------------- weight prep
// W[K][O] fp32 -> Wt_hi[O][K], Wt_lo[O][K] bf16 (transposed + hi/lo split)

struct WSpec { const float* W; ushort* hi; ushort* lo; int K; int O; };
struct WPack { WSpec s[9]; };

__global__ void k_wprep(WPack p) {
  const WSpec w = p.s[blockIdx.y];
  const int total = w.K * w.O;
  for (int i = blockIdx.x * 256 + threadIdx.x; i < total; i += gridDim.x * 256) {
    const int o = i / w.K;
    const int k = i - o * w.K;
    const float v = w.W[(size_t)k * w.O + o];
    const ushort h = f2bf_rne(v);
    w.hi[i] = h;
    w.lo[i] = f2bf_rne(v - bf2f(h));
  }
}

// ---------------------------------------------------------------- MFMA split-bf16 GEMM
// C[N,O] = op(A)[N,K] @ W[K,O] (+ bias)
// op(A) = PRO ? lrelu(A*scale + shift) : A  (ss[0..K) scale, ss[K..2K) shift)
// W passed as pre-split transposed bf16: Whi/Wlo[O][K].
// acc via 3 MFMAs per fragment pair: ah*bh + ah*bl + al*bh.

template <int K, int O, bool PRO, bool BIAS, bool OUTBF>
__launch_bounds__(256, 2)
__global__ void k_gemm_mfma(const float* __restrict__ A, const ushort* __restrict__ Whi,
                            const ushort* __restrict__ Wlo, const float* __restrict__ bias,
                            const float* __restrict__ ss, void* __restrict__ Cout, int N) {
  constexpr int BN = (O >= 128) ? 128 : O;  // 128 or 64
  constexpr int KS = K / 32;
  constexpr int WC = (BN == 128) ? 2 : 1;   // wave grid cols (64-wide each)
  constexpr int WR = 4 / WC;                // wave grid rows
  constexpr int MF = (128 / WR) / 16;       // 16-row frags per wave (4 or 2)
  constexpr int NF = 4;                     // 64 cols / 16

  __shared__ __align__(16) ushort AsH[128][32];
  __shared__ __align__(16) ushort AsL[128][32];

  const int bm = blockIdx.x * 128;
  const int bo = blockIdx.y * BN;
  const int t = threadIdx.x;
  const int w = t >> 6, l = t & 63;
  const int wr = w / WC, wc = w % WC;
  const int r0 = wr * (128 / WR);
  const int c0 = wc * 64;
  const int lr = l & 15;         // fragment row/col lane index
  const int lk = (l >> 4) * 8;   // fragment k base (8 contiguous bf16)

  f32x4 acc[MF][NF];
  const f32x4 zero4 = {0.f, 0.f, 0.f, 0.f};
#pragma unroll
  for (int mf = 0; mf < MF; ++mf)
#pragma unroll
    for (int nf = 0; nf < NF; ++nf) acc[mf][nf] = zero4;

  // A staging indices: thread -> (row = ar + 32p, cols ac..ac+3)
  const int ar = t >> 3;
  const int ac = (t & 7) * 4;

  for (int ks = 0; ks < KS; ++ks) {
    // ---- load A tile 128x32 fp32, apply prologue
    float4 va[4];
#pragma unroll
    for (int p = 0; p < 4; ++p) {
      const int row = bm + ar + p * 32;
      float4 v = make_float4(0.f, 0.f, 0.f, 0.f);
      if (row < N) v = *reinterpret_cast<const float4*>(&A[(size_t)row * K + ks * 32 + ac]);
      if (PRO) {
        const float4 sc = *reinterpret_cast<const float4*>(&ss[ks * 32 + ac]);
        const float4 sh = *reinterpret_cast<const float4*>(&ss[K + ks * 32 + ac]);
        v.x = v.x * sc.x + sh.x; v.x = v.x > 0.f ? v.x : 0.01f * v.x;
        v.y = v.y * sc.y + sh.y; v.y = v.y > 0.f ? v.y : 0.01f * v.y;
        v.z = v.z * sc.z + sh.z; v.z = v.z > 0.f ? v.z : 0.01f * v.z;
        v.w = v.w * sc.w + sh.w; v.w = v.w > 0.f ? v.w : 0.01f * v.w;
      }
      va[p] = v;
    }
    __syncthreads();  // previous iteration's LDS reads complete
#pragma unroll
    for (int p = 0; p < 4; ++p) {
      const float4 v = va[p];
      ushort4 h4;
      h4.x = f2bf_rne(v.x); h4.y = f2bf_rne(v.y); h4.z = f2bf_rne(v.z); h4.w = f2bf_rne(v.w);
      ushort4 l4;
      l4.x = f2bf_rne(v.x - bf2f(h4.x));
      l4.y = f2bf_rne(v.y - bf2f(h4.y));
      l4.z = f2bf_rne(v.z - bf2f(h4.z));
      l4.w = f2bf_rne(v.w - bf2f(h4.w));
      *reinterpret_cast<ushort4*>(&AsH[ar + p * 32][ac]) = h4;
      *reinterpret_cast<ushort4*>(&AsL[ar + p * 32][ac]) = l4;
    }
    __syncthreads();

    // ---- B fragments straight from global (L2-hot, pre-transposed split W)
    short8 bh[NF], bl[NF];
#pragma unroll
    for (int nf = 0; nf < NF; ++nf) {
      const size_t off = (size_t)(bo + c0 + nf * 16 + lr) * K + ks * 32 + lk;
      bh[nf] = *reinterpret_cast<const short8*>(&Whi[off]);
      bl[nf] = *reinterpret_cast<const short8*>(&Wlo[off]);
    }

    // ---- A fragments from LDS + MFMA
#pragma unroll
    for (int mf = 0; mf < MF; ++mf) {
      const short8 ah = *reinterpret_cast<const short8*>(&AsH[r0 + mf * 16 + lr][lk]);
      const short8 al = *reinterpret_cast<const short8*>(&AsL[r0 + mf * 16 + lr][lk]);
#pragma unroll
      for (int nf = 0; nf < NF; ++nf) {
        acc[mf][nf] = __builtin_amdgcn_mfma_f32_16x16x32_bf16(ah, bh[nf], acc[mf][nf], 0, 0, 0);
        acc[mf][nf] = __builtin_amdgcn_mfma_f32_16x16x32_bf16(ah, bl[nf], acc[mf][nf], 0, 0, 0);
        acc[mf][nf] = __builtin_amdgcn_mfma_f32_16x16x32_bf16(al, bh[nf], acc[mf][nf], 0, 0, 0);
      }
    }
  }

  // ---- epilogue: C[row = bm+r0+mf*16+(l>>4)*4+rg][col = bo+c0+nf*16+lr]
#pragma unroll
  for (int mf = 0; mf < MF; ++mf) {
    const int gr0 = bm + r0 + mf * 16 + (l >> 4) * 4;
#pragma unroll
    for (int nf = 0; nf < NF; ++nf) {
      const int gc = bo + c0 + nf * 16 + lr;
      float bval = 0.f;
      if (BIAS) bval = bias[gc];
#pragma unroll
      for (int rg = 0; rg < 4; ++rg) {
        const int row = gr0 + rg;
        if (row < N) {
          const float v = acc[mf][nf][rg] + bval;
          if (OUTBF)
            ((ushort*)Cout)[(size_t)row * O + gc] = f2bf_rne(v);
          else
            ((float*)Cout)[(size_t)row * O + gc] = v;
        }
      }
    }
  }
}

// ---------------------------------------------------------------- BN column stats

template <int H>
__global__ void k_colstats(const float* __restrict__ X, int n, float* __restrict__ sums) {
  constexpr int NSUB = 256 / H;
  const int t = threadIdx.x;
  const int c = t % H;
  const int sub = t / H;
  const int r0 = blockIdx.x * 256;
  float s = 0.f, s2 = 0.f;
  const int rend = (r0 + 256 < n) ? r0 + 256 : n;
  for (int r = r0 + sub; r < rend; r += NSUB) {
    const float v = X[(size_t)r * H + c];
    s += v;
    s2 += v * v;
  }
  atomicAdd(&sums[c], s);
  atomicAdd(&sums[H + c], s2);
}

__global__ void k_bnfin(const float* __restrict__ sums, const float* __restrict__ g,
                        const float* __restrict__ b, float* __restrict__ ss, int H, float invN) {
  const int c = threadIdx.x;
  if (c < H) {
    const float mean = sums[c] * invN;
    float var = sums[H + c] * invN - mean * mean;
    var = var < 0.f ? 0.f : var;
    const float sc = g[c] * rsqrtf(var + 1e-5f);
    ss[c] = sc;
    ss[H + c] = b[c] - mean * sc;
  }
}

// ---------------------------------------------------------------- GCN aggregation (bf16 in)
// out[d] = sum_{e:(s->d)} Hin[s]*dis[s]*dis[d] + Hin[d]*dis[d]^2 + bias

template <int H>
__launch_bounds__(256)
__global__ void k_agg_bf(const ushort* __restrict__ Hin, const int* __restrict__ row_ptr,
                         const int* __restrict__ col, const float* __restrict__ dis,
                         const float* __restrict__ bias, float* __restrict__ out, int n) {
  constexpr int V = H / 64;
  const int lane = threadIdx.x & 63;
  const int node = blockIdx.x * 4 + (threadIdx.x >> 6);
  if (node >= n) return;
  const int beg = row_ptr[node];
  const int end = row_ptr[node + 1];
  const float dd = dis[node];
  float acc[V];
#pragma unroll
  for (int j = 0; j < V; ++j) acc[j] = 0.f;
  for (int e = beg; e < end; ++e) {
    const int s = col[e];
    const float w = dis[s] * dd;
    const ushort* hp = &Hin[(size_t)s * H + lane * V];
    if constexpr (V == 4) {
      const ushort4 u = *reinterpret_cast<const ushort4*>(hp);
      acc[0] += bf2f(u.x) * w; acc[1] += bf2f(u.y) * w;
      acc[2] += bf2f(u.z) * w; acc[3] += bf2f(u.w) * w;
    } else {
      const ushort2 u = *reinterpret_cast<const ushort2*>(hp);
      acc[0] += bf2f(u.x) * w; acc[1] += bf2f(u.y) * w;
    }
  }
  const float sw = dd * dd;
  const ushort* hs = &Hin[(size_t)node * H + lane * V];
#pragma unroll
  for (int j = 0; j < V; ++j) acc[j] += bf2f(hs[j]) * sw;
  float* op = &out[(size_t)node * H + lane * V];
#pragma unroll
  for (int j = 0; j < V; ++j) op[j] = acc[j] + bias[lane * V + j];
}

// ---------------------------------------------------------------- residual combine
// xin = (BN(xin) + h) * 2^-0.5 + xin

template <int H>
__global__ void k_combine(float* __restrict__ xin, const float* __restrict__ h,
                          const float* __restrict__ ss, int total) {
  const float cinv = 0.70710678118654752f;
  int i = blockIdx.x * blockDim.x + threadIdx.x;
  if (i < total) {
    const int c = i & (H - 1);
    const float v = xin[i];
    const float bn = v * ss[c] + ss[H + c];
    xin[i] = (bn + h[i]) * cinv + v;
  }
}

// ---------------------------------------------------------------- launch

extern "C" void kernel_launch(void* const* d_in, const int* in_sizes, int n_in,
                              void* d_out, int out_size, void* d_ws, size_t ws_size,
                              hipStream_t stream) {
  const int N = in_sizes[0] / 128;
  const int E = in_sizes[1] / 2;

  const float* x_vert = (const float*)d_in[0];
  const int* src = (const int*)d_in[1];
  const int* dst = src + E;
  const float* g1_lin_W = (const float*)d_in[2];
  const float* g1_lin_b = (const float*)d_in[3];
  const float* g1_c1_W = (const float*)d_in[4];
  const float* g1_c1_b = (const float*)d_in[5];
  const float* g1_c2_W = (const float*)d_in[6];
  const float* g1_c2_b = (const float*)d_in[7];
  const float* g1_n1_g = (const float*)d_in[8];
  const float* g1_n1_b = (const float*)d_in[9];
  const float* g1_n2_g = (const float*)d_in[10];
  const float* g1_n2_b = (const float*)d_in[11];
  const float* g2_lin_W = (const float*)d_in[12];
  const float* g2_lin_b = (const float*)d_in[13];
  const float* g2_c1_W = (const float*)d_in[14];
  const float* g2_c1_b = (const float*)d_in[15];
  const float* g2_c2_W = (const float*)d_in[16];
  const float* g2_c2_b = (const float*)d_in[17];
  const float* g2_n1_g = (const float*)d_in[18];
  const float* g2_n1_b = (const float*)d_in[19];
  const float* g2_n2_g = (const float*)d_in[20];
  const float* g2_n2_b = (const float*)d_in[21];
  const float* out_W = (const float*)d_in[22];
  const float* out_b = (const float*)d_in[23];
  const float* n1_g = (const float*)d_in[24];
  const float* n1_b = (const float*)d_in[25];
  const float* l1_W = (const float*)d_in[26];
  const float* l1_b = (const float*)d_in[27];
  const float* n2_g = (const float*)d_in[28];
  const float* n2_b = (const float*)d_in[29];
  const float* l2_W = (const float*)d_in[30];
  const float* l2_b = (const float*)d_in[31];

  float* out = (float*)d_out;

  // ---- workspace carve-up
  size_t off = 0;
  auto alloc = [&](size_t bytes) -> void* {
    void* p = (char*)d_ws + off;
    off += (bytes + 255) & ~(size_t)255;
    return p;
  };
  float* B1 = (float*)alloc((size_t)N * 256 * 4);
  float* B2 = (float*)alloc((size_t)N * 256 * 4);
  float* B3 = (float*)alloc((size_t)N * 256 * 4);
  int* cnt = (int*)alloc((size_t)N * 4);
  int* row_ptr = (int*)alloc((size_t)(N + 1) * 4);
  int* cursor = (int*)alloc((size_t)N * 4);
  int* col = (int*)alloc((size_t)E * 4);
  int* part = (int*)alloc(1024 * 4);
  float* dis = (float*)alloc((size_t)N * 4);
  float* sums = (float*)alloc(6 * 512 * 4);  // 6 independent stats slots
  float* ssv = (float*)alloc(6 * 512 * 4);   // 6 scale/shift slots

  // split-transposed weights (bf16 hi/lo)
  const int wk[9] = {128, 256, 256, 256, 128, 128, 128, 128, 64};
  const int wo[9] = {256, 256, 256, 128, 128, 128, 128, 64, 64};
  const float* wsrc[9] = {g1_lin_W, g1_c1_W, g1_c2_W, g2_lin_W, g2_c1_W,
                          g2_c2_W, out_W, l1_W, l2_W};
  ushort* whi[9];
  ushort* wlo[9];
  for (int i = 0; i < 9; ++i) {
    whi[i] = (ushort*)alloc((size_t)wk[i] * wo[i] * 2);
    wlo[i] = (ushort*)alloc((size_t)wk[i] * wo[i] * 2);
  }
  (void)ws_size;
  (void)n_in;
  (void)out_size;

  // bf16 aliases over dead fp32 regions
  ushort* bb2 = (ushort*)B2;  // used while B2-as-fp32 is dead (block 1)
  ushort* bb3 = (ushort*)B3;  // used while B3-as-fp32 is dead (block 2)

  const int NB = IDIV(N, 256);
  const float invN = 1.0f / (float)N;

  // ---- CSR build + weight prep
  k_zero_i32<<<NB, 256, 0, stream>>>(cnt, N);
  k_zero_f32<<<IDIV(6 * 512, 256), 256, 0, stream>>>(sums, 6 * 512);
  {
    WPack p;
    for (int i = 0; i < 9; ++i) p.s[i] = WSpec{wsrc[i], whi[i], wlo[i], wk[i], wo[i]};
    k_wprep<<<dim3(64, 9), 256, 0, stream>>>(p);
  }
  k_count<<<IDIV(E, 256), 256, 0, stream>>>(dst, E, cnt);
  k_scan_partial<<<NB, 256, 0, stream>>>(cnt, N, part);
  k_scan_offsets<<<1, 256, 0, stream>>>(part, NB);
  k_scan_final<<<NB, 256, 0, stream>>>(cnt, N, part, row_ptr);
  k_cursor_dis<<<NB, 256, 0, stream>>>(row_ptr, cnt, cursor, dis, row_ptr + N, N, E);
  k_scatter<<<IDIV(E, 256), 256, 0, stream>>>(src, dst, E, cursor, col);

  const int GM = IDIV(N, 128);
  float* ss0 = ssv + 0 * 512;
  float* ss1 = ssv + 1 * 512;
  float* ss2 = ssv + 2 * 512;
  float* ss3 = ssv + 3 * 512;
  float* ss4 = ssv + 4 * 512;
  float* ss5 = ssv + 5 * 512;

  // ================= block 1 (in 128, hid 256) =================
  k_gemm_mfma<128, 256, false, true, false>
      <<<dim3(GM, 2), 256, 0, stream>>>(x_vert, whi[0], wlo[0], g1_lin_b, nullptr, B1, N);
  k_colstats<256><<<NB, 256, 0, stream>>>(B1, N, sums + 0 * 512);
  k_bnfin<<<1, 256, 0, stream>>>(sums + 0 * 512, g1_n1_g, g1_n1_b, ss0, 256, invN);
  k_gemm_mfma<256, 256, true, false, true>
      <<<dim3(GM, 2), 256, 0, stream>>>(B1, whi[1], wlo[1], nullptr, ss0, bb2, N);
  k_agg_bf<256><<<IDIV(N, 4), 256, 0, stream>>>(bb2, row_ptr, col, dis, g1_c1_b, B3, N);
  k_colstats<256><<<NB, 256, 0, stream>>>(B3, N, sums + 1 * 512);
  k_bnfin<<<1, 256, 0, stream>>>(sums + 1 * 512, g1_n2_g, g1_n2_b, ss1, 256, invN);
  k_gemm_mfma<256, 256, true, false, true>
      <<<dim3(GM, 2), 256, 0, stream>>>(B3, whi[2], wlo[2], nullptr, ss1, bb2, N);
  k_agg_bf<256><<<IDIV(N, 4), 256, 0, stream>>>(bb2, row_ptr, col, dis, g1_c2_b, B3, N);
  k_combine<256><<<IDIV(N * 256, 256), 256, 0, stream>>>(B1, B3, ss0, N * 256);

  // ================= block 2 (in 256, hid 128) =================
  k_gemm_mfma<256, 128, false, true, false>
      <<<dim3(GM, 1), 256, 0, stream>>>(B1, whi[3], wlo[3], g2_lin_b, nullptr, B2, N);
  k_colstats<128><<<NB, 256, 0, stream>>>(B2, N, sums + 2 * 512);
  k_bnfin<<<1, 256, 0, stream>>>(sums + 2 * 512, g2_n1_g, g2_n1_b, ss2, 128, invN);
  k_gemm_mfma<128, 128, true, false, true>
      <<<dim3(GM, 1), 256, 0, stream>>>(B2, whi[4], wlo[4], nullptr, ss2, bb3, N);
  k_agg_bf<128><<<IDIV(N, 4), 256, 0, stream>>>(bb3, row_ptr, col, dis, g2_c1_b, B1, N);
  k_colstats<128><<<NB, 256, 0, stream>>>(B1, N, sums + 3 * 512);
  k_bnfin<<<1, 256, 0, stream>>>(sums + 3 * 512, g2_n2_g, g2_n2_b, ss3, 128, invN);
  k_gemm_mfma<128, 128, true, false, true>
      <<<dim3(GM, 1), 256, 0, stream>>>(B1, whi[5], wlo[5], nullptr, ss3, bb3, N);
  k_agg_bf<128><<<IDIV(N, 4), 256, 0, stream>>>(bb3, row_ptr, col, dis, g2_c2_b, B1, N);
  k_combine<128><<<IDIV(N * 128, 256), 256, 0, stream>>>(B2, B1, ss2, N * 128);

  // ================= head =================
  k_gemm_mfma<128, 128, false, true, false>
      <<<dim3(GM, 1), 256, 0, stream>>>(B2, whi[6], wlo[6], out_b, nullptr, B1, N);
  k_colstats<128><<<NB, 256, 0, stream>>>(B1, N, sums + 4 * 512);
  k_bnfin<<<1, 256, 0, stream>>>(sums + 4 * 512, n1_g, n1_b, ss4, 128, invN);
  k_gemm_mfma<128, 64, true, true, false>
      <<<dim3(GM, 1), 256, 0, stream>>>(B1, whi[7], wlo[7], l1_b, ss4, B3, N);
  k_colstats<64><<<NB, 256, 0, stream>>>(B3, N, sums + 5 * 512);
  k_bnfin<<<1, 256, 0, stream>>>(sums + 5 * 512, n2_g, n2_b, ss5, 64, invN);
  k_gemm_mfma<64, 64, true, true, false>
      <<<dim3(GM, 1), 256, 0, stream>>>(B3, whi[8], wlo[8], l2_b, ss5, out, N);
}

// Round 3
// 832.758 us; speedup vs baseline: 1.5207x; 1.3184x over previous
//
#include <hip/hip_runtime.h>
#include <cstddef>
#include <cstdint>

#define IDIV(a, b) (((a) + (b) - 1) / (b))

typedef __attribute__((ext_vector_type(8))) short short8;
typedef __attribute__((ext_vector_type(8))) unsigned short ushort8v;
typedef __attribute__((ext_vector_type(4))) float f32x4;

__device__ inline ushort f2bf_rne(float x) {
  uint32_t u = __builtin_bit_cast(uint32_t, x);
  u += 0x7fff + ((u >> 16) & 1);
  return (ushort)(u >> 16);
}
__device__ inline float bf2f(ushort h) {
  uint32_t u = (uint32_t)h << 16;
  return __builtin_bit_cast(float, u);
}

// ---------------------------------------------------------------- utilities

__global__ void k_zero_i32(int* __restrict__ p, int n) {
  int i = blockIdx.x * blockDim.x + threadIdx.x;
  if (i < n) p[i] = 0;
}

__global__ void k_zero_f32(float* __restrict__ p, int n) {
  int i = blockIdx.x * blockDim.x + threadIdx.x;
  if (i < n) p[i] = 0.f;
}

// ---------------------------------------------------------------- CSR build

__global__ void k_count(const int* __restrict__ dst, int E, int* __restrict__ cnt) {
  int i = blockIdx.x * blockDim.x + threadIdx.x;
  if (i < E) atomicAdd(&cnt[dst[i]], 1);
}

__global__ void k_scan_partial(const int* __restrict__ cnt, int n, int* __restrict__ part) {
  __shared__ int sm[256];
  const int t = threadIdx.x;
  const int i = blockIdx.x * 256 + t;
  sm[t] = (i < n) ? cnt[i] : 0;
  __syncthreads();
  for (int off = 128; off > 0; off >>= 1) {
    if (t < off) sm[t] += sm[t + off];
    __syncthreads();
  }
  if (t == 0) part[blockIdx.x] = sm[0];
}

__global__ void k_scan_offsets(int* __restrict__ part, int nb) {
  __shared__ int sm[256];
  const int t = threadIdx.x;
  if (t < nb) sm[t] = part[t];
  __syncthreads();
  if (t == 0) {
    int run = 0;
    for (int i = 0; i < nb; ++i) { int v = sm[i]; sm[i] = run; run += v; }
  }
  __syncthreads();
  if (t < nb) part[t] = sm[t];
}

__global__ void k_scan_final(const int* __restrict__ cnt, int n, const int* __restrict__ part,
                             int* __restrict__ row_ptr) {
  __shared__ int sm[256];
  const int t = threadIdx.x;
  const int i = blockIdx.x * 256 + t;
  const int v = (i < n) ? cnt[i] : 0;
  sm[t] = v;
  __syncthreads();
  for (int off = 1; off < 256; off <<= 1) {
    int x = (t >= off) ? sm[t - off] : 0;
    __syncthreads();
    sm[t] += x;
    __syncthreads();
  }
  if (i < n) row_ptr[i] = part[blockIdx.x] + sm[t] - v;  // exclusive scan
}

__global__ void k_cursor_dis(const int* __restrict__ row_ptr, const int* __restrict__ cnt,
                             int* __restrict__ cursor, float* __restrict__ dis,
                             int* __restrict__ row_ptr_end, int n, int E) {
  int i = blockIdx.x * blockDim.x + threadIdx.x;
  if (i == 0) *row_ptr_end = E;
  if (i < n) {
    cursor[i] = row_ptr[i];
    dis[i] = rsqrtf((float)cnt[i] + 1.0f);
  }
}

__global__ void k_scatter(const int* __restrict__ src, const int* __restrict__ dst, int E,
                          int* __restrict__ cursor, int* __restrict__ col) {
  int i = blockIdx.x * blockDim.x + threadIdx.x;
  if (i < E) {
    int d = dst[i];
    int pos = atomicAdd(&cursor[d], 1);
    col[pos] = src[i];
  }
}

// ---------------------------------------------------------------- weight prep
// W[K][O] fp32 -> Wt_hi[O][K], Wt_lo[O][K] bf16 (transposed + hi/lo split)

struct WSpec { const float* W; ushort* hi; ushort* lo; int K; int O; };
struct WPack { WSpec s[9]; };

__global__ void k_wprep(WPack p) {
  const WSpec w = p.s[blockIdx.y];
  const int total = w.K * w.O;
  for (int i = blockIdx.x * 256 + threadIdx.x; i < total; i += gridDim.x * 256) {
    const int o = i / w.K;
    const int k = i - o * w.K;
    const float v = w.W[(size_t)k * w.O + o];
    const ushort h = f2bf_rne(v);
    w.hi[i] = h;
    w.lo[i] = f2bf_rne(v - bf2f(h));
  }
}

// ---------------------------------------------------------------- MFMA split-bf16 GEMM
// C[N,O] = op(A)[N,K] @ W[K,O] (+ bias); op = PRO ? lrelu(A*sc+sh) : A
// Double-buffered LDS (1 barrier/k-step), next-tile global load issued before
// the MFMA cluster; prologue+convert deferred until after MFMAs.

template <int K, int O, bool PRO, bool BIAS, bool OUTBF>
__launch_bounds__(256, 3)
__global__ void k_gemm_mfma(const float* __restrict__ A, const ushort* __restrict__ Whi,
                            const ushort* __restrict__ Wlo, const float* __restrict__ bias,
                            const float* __restrict__ ss, void* __restrict__ Cout, int N) {
  constexpr int BN = (O >= 128) ? 128 : O;  // 128 or 64
  constexpr int KS = K / 32;
  constexpr int WC = (BN == 128) ? 2 : 1;
  constexpr int WR = 4 / WC;
  constexpr int MF = (128 / WR) / 16;
  constexpr int NF = 4;
  constexpr int LDP = 40;  // padded row: 80B stride -> 2-way bank alias (free)

  __shared__ __align__(16) ushort AsH[2][128][LDP];
  __shared__ __align__(16) ushort AsL[2][128][LDP];

  const int bm = blockIdx.x * 128;
  const int bo = blockIdx.y * BN;
  const int t = threadIdx.x;
  const int w = t >> 6, l = t & 63;
  const int wr = w / WC, wc = w % WC;
  const int r0 = wr * (128 / WR);
  const int c0 = wc * 64;
  const int lr = l & 15;
  const int lk = (l >> 4) * 8;

  // A staging: thread t covers row ar = t>>1, 16 cols starting at acol
  const int ar = t >> 1;
  const int acol = (t & 1) * 16;
  const int arow = bm + ar;

  f32x4 acc[MF][NF];
  const f32x4 zero4 = {0.f, 0.f, 0.f, 0.f};
#pragma unroll
  for (int mf = 0; mf < MF; ++mf)
#pragma unroll
    for (int nf = 0; nf < NF; ++nf) acc[mf][nf] = zero4;

  float4 va[4];

  auto loadA = [&](int ks, float4 v[4]) {
    if (arow < N) {
#pragma unroll
      for (int q = 0; q < 4; ++q)
        v[q] = *reinterpret_cast<const float4*>(&A[(size_t)arow * K + ks * 32 + acol + q * 4]);
    } else {
#pragma unroll
      for (int q = 0; q < 4; ++q) v[q] = make_float4(0.f, 0.f, 0.f, 0.f);
    }
  };

  auto stageA = [&](int buf, int ks, float4 v[4]) {
    if (PRO) {
#pragma unroll
      for (int q = 0; q < 4; ++q) {
        const float4 sc = *reinterpret_cast<const float4*>(&ss[ks * 32 + acol + q * 4]);
        const float4 sh = *reinterpret_cast<const float4*>(&ss[K + ks * 32 + acol + q * 4]);
        float4& x = v[q];
        x.x = x.x * sc.x + sh.x; x.x = x.x > 0.f ? x.x : 0.01f * x.x;
        x.y = x.y * sc.y + sh.y; x.y = x.y > 0.f ? x.y : 0.01f * x.y;
        x.z = x.z * sc.z + sh.z; x.z = x.z > 0.f ? x.z : 0.01f * x.z;
        x.w = x.w * sc.w + sh.w; x.w = x.w > 0.f ? x.w : 0.01f * x.w;
      }
    }
    float f[16] = {v[0].x, v[0].y, v[0].z, v[0].w, v[1].x, v[1].y, v[1].z, v[1].w,
                   v[2].x, v[2].y, v[2].z, v[2].w, v[3].x, v[3].y, v[3].z, v[3].w};
    ushort8v h0, l0, h1, l1;
#pragma unroll
    for (int j = 0; j < 8; ++j) {
      ushort h = f2bf_rne(f[j]);
      h0[j] = h;
      l0[j] = f2bf_rne(f[j] - bf2f(h));
    }
#pragma unroll
    for (int j = 0; j < 8; ++j) {
      ushort h = f2bf_rne(f[8 + j]);
      h1[j] = h;
      l1[j] = f2bf_rne(f[8 + j] - bf2f(h));
    }
    *reinterpret_cast<ushort8v*>(&AsH[buf][ar][acol]) = h0;
    *reinterpret_cast<ushort8v*>(&AsH[buf][ar][acol + 8]) = h1;
    *reinterpret_cast<ushort8v*>(&AsL[buf][ar][acol]) = l0;
    *reinterpret_cast<ushort8v*>(&AsL[buf][ar][acol + 8]) = l1;
  };

  loadA(0, va);
  stageA(0, 0, va);
  __syncthreads();

  for (int ks = 0; ks < KS; ++ks) {
    const int cur = ks & 1;
    float4 van[4];
    if (ks + 1 < KS) loadA(ks + 1, van);  // issue global loads early

    short8 bh[NF], bl[NF];
#pragma unroll
    for (int nf = 0; nf < NF; ++nf) {
      const size_t boff = (size_t)(bo + c0 + nf * 16 + lr) * K + ks * 32 + lk;
      bh[nf] = *reinterpret_cast<const short8*>(&Whi[boff]);
      bl[nf] = *reinterpret_cast<const short8*>(&Wlo[boff]);
    }

#pragma unroll
    for (int mf = 0; mf < MF; ++mf) {
      const short8 ah = *reinterpret_cast<const short8*>(&AsH[cur][r0 + mf * 16 + lr][lk]);
      const short8 al = *reinterpret_cast<const short8*>(&AsL[cur][r0 + mf * 16 + lr][lk]);
#pragma unroll
      for (int nf = 0; nf < NF; ++nf) {
        acc[mf][nf] = __builtin_amdgcn_mfma_f32_16x16x32_bf16(ah, bh[nf], acc[mf][nf], 0, 0, 0);
        acc[mf][nf] = __builtin_amdgcn_mfma_f32_16x16x32_bf16(ah, bl[nf], acc[mf][nf], 0, 0, 0);
        acc[mf][nf] = __builtin_amdgcn_mfma_f32_16x16x32_bf16(al, bh[nf], acc[mf][nf], 0, 0, 0);
      }
    }

    if (ks + 1 < KS) stageA(cur ^ 1, ks + 1, van);  // convert+write after MFMAs
    __syncthreads();
  }

  // epilogue: C[row = bm+r0+mf*16+(l>>4)*4+rg][col = bo+c0+nf*16+lr]
#pragma unroll
  for (int mf = 0; mf < MF; ++mf) {
    const int gr0 = bm + r0 + mf * 16 + (l >> 4) * 4;
#pragma unroll
    for (int nf = 0; nf < NF; ++nf) {
      const int gc = bo + c0 + nf * 16 + lr;
      float bval = 0.f;
      if (BIAS) bval = bias[gc];
#pragma unroll
      for (int rg = 0; rg < 4; ++rg) {
        const int row = gr0 + rg;
        if (row < N) {
          const float v = acc[mf][nf][rg] + bval;
          if (OUTBF)
            ((ushort*)Cout)[(size_t)row * O + gc] = f2bf_rne(v);
          else
            ((float*)Cout)[(size_t)row * O + gc] = v;
        }
      }
    }
  }
}

// ---------------------------------------------------------------- BN column stats
// float4 loads + LDS cross-sub reduction, then one atomic pair per column

template <int H>
__launch_bounds__(256)
__global__ void k_colstats(const float* __restrict__ X, int n, float* __restrict__ sums) {
  constexpr int G = H / 4;      // column groups of 4
  constexpr int NS = 256 / G;   // row subgroups
  const int t = threadIdx.x;
  const int cg = t % G;
  const int sub = t / G;
  const int r0 = blockIdx.x * 256;
  const int rend = (r0 + 256 < n) ? r0 + 256 : n;
  float4 s = make_float4(0.f, 0.f, 0.f, 0.f);
  float4 s2 = make_float4(0.f, 0.f, 0.f, 0.f);
  for (int r = r0 + sub; r < rend; r += NS) {
    const float4 v = *reinterpret_cast<const float4*>(&X[(size_t)r * H + cg * 4]);
    s.x += v.x; s.y += v.y; s.z += v.z; s.w += v.w;
    s2.x += v.x * v.x; s2.y += v.y * v.y; s2.z += v.z * v.z; s2.w += v.w * v.w;
  }
  __shared__ float red[256][8];
  red[t][0] = s.x; red[t][1] = s.y; red[t][2] = s.z; red[t][3] = s.w;
  red[t][4] = s2.x; red[t][5] = s2.y; red[t][6] = s2.z; red[t][7] = s2.w;
  __syncthreads();
  if (sub == 0) {
#pragma unroll
    for (int k = 1; k < NS; ++k) {
      const int u = cg + k * G;
      s.x += red[u][0]; s.y += red[u][1]; s.z += red[u][2]; s.w += red[u][3];
      s2.x += red[u][4]; s2.y += red[u][5]; s2.z += red[u][6]; s2.w += red[u][7];
    }
    atomicAdd(&sums[cg * 4 + 0], s.x);
    atomicAdd(&sums[cg * 4 + 1], s.y);
    atomicAdd(&sums[cg * 4 + 2], s.z);
    atomicAdd(&sums[cg * 4 + 3], s.w);
    atomicAdd(&sums[H + cg * 4 + 0], s2.x);
    atomicAdd(&sums[H + cg * 4 + 1], s2.y);
    atomicAdd(&sums[H + cg * 4 + 2], s2.z);
    atomicAdd(&sums[H + cg * 4 + 3], s2.w);
  }
}

__global__ void k_bnfin(const float* __restrict__ sums, const float* __restrict__ g,
                        const float* __restrict__ b, float* __restrict__ ss, int H, float invN) {
  const int c = threadIdx.x;
  if (c < H) {
    const float mean = sums[c] * invN;
    float var = sums[H + c] * invN - mean * mean;
    var = var < 0.f ? 0.f : var;
    const float sc = g[c] * rsqrtf(var + 1e-5f);
    ss[c] = sc;
    ss[H + c] = b[c] - mean * sc;
  }
}

// ---------------------------------------------------------------- GCN aggregation (bf16 in)
// out[d] = sum_{e:(s->d)} Hin[s]*dis[s]*dis[d] + Hin[d]*dis[d]^2 + bias
// 4-wide batched edge loop (masked tail batch) for 4 outstanding gather chains.

template <int H>
__launch_bounds__(256)
__global__ void k_agg_bf(const ushort* __restrict__ Hin, const int* __restrict__ row_ptr,
                         const int* __restrict__ col, const float* __restrict__ dis,
                         const float* __restrict__ bias, float* __restrict__ out, int n) {
  constexpr int V = H / 64;
  const int lane = threadIdx.x & 63;
  const int node = blockIdx.x * 4 + (threadIdx.x >> 6);
  if (node >= n) return;
  const int beg = row_ptr[node];
  const int end = row_ptr[node + 1];
  const float dd = dis[node];
  const int lv = lane * V;
  float acc[V];
#pragma unroll
  for (int j = 0; j < V; ++j) acc[j] = 0.f;

  for (int e = beg; e < end; e += 4) {
    int s[4];
    float w[4];
#pragma unroll
    for (int i = 0; i < 4; ++i) {
      const bool valid = (e + i) < end;
      s[i] = col[valid ? e + i : beg];
      w[i] = valid ? dd : 0.f;
    }
#pragma unroll
    for (int i = 0; i < 4; ++i) w[i] *= dis[s[i]];
    if constexpr (V == 4) {
      ushort4 u[4];
#pragma unroll
      for (int i = 0; i < 4; ++i)
        u[i] = *reinterpret_cast<const ushort4*>(&Hin[(size_t)s[i] * H + lv]);
#pragma unroll
      for (int i = 0; i < 4; ++i) {
        acc[0] += bf2f(u[i].x) * w[i];
        acc[1] += bf2f(u[i].y) * w[i];
        acc[2] += bf2f(u[i].z) * w[i];
        acc[3] += bf2f(u[i].w) * w[i];
      }
    } else {
      ushort2 u[4];
#pragma unroll
      for (int i = 0; i < 4; ++i)
        u[i] = *reinterpret_cast<const ushort2*>(&Hin[(size_t)s[i] * H + lv]);
#pragma unroll
      for (int i = 0; i < 4; ++i) {
        acc[0] += bf2f(u[i].x) * w[i];
        acc[1] += bf2f(u[i].y) * w[i];
      }
    }
  }

  const float sw = dd * dd;
  if constexpr (V == 4) {
    const ushort4 u = *reinterpret_cast<const ushort4*>(&Hin[(size_t)node * H + lv]);
    acc[0] += bf2f(u.x) * sw; acc[1] += bf2f(u.y) * sw;
    acc[2] += bf2f(u.z) * sw; acc[3] += bf2f(u.w) * sw;
    const float4 bv = *reinterpret_cast<const float4*>(&bias[lv]);
    float4 o;
    o.x = acc[0] + bv.x; o.y = acc[1] + bv.y; o.z = acc[2] + bv.z; o.w = acc[3] + bv.w;
    *reinterpret_cast<float4*>(&out[(size_t)node * H + lv]) = o;
  } else {
    const ushort2 u = *reinterpret_cast<const ushort2*>(&Hin[(size_t)node * H + lv]);
    acc[0] += bf2f(u.x) * sw; acc[1] += bf2f(u.y) * sw;
    const float2 bv = *reinterpret_cast<const float2*>(&bias[lv]);
    float2 o;
    o.x = acc[0] + bv.x; o.y = acc[1] + bv.y;
    *reinterpret_cast<float2*>(&out[(size_t)node * H + lv]) = o;
  }
}

// ---------------------------------------------------------------- residual combine
// xin = (BN(xin) + h) * 2^-0.5 + xin   (float4 per thread)

template <int H>
__global__ void k_combine4(float* __restrict__ xin, const float* __restrict__ h,
                           const float* __restrict__ ss, int total4) {
  const float cinv = 0.70710678118654752f;
  int i = blockIdx.x * blockDim.x + threadIdx.x;
  if (i < total4) {
    const int c4 = (i & (H / 4 - 1)) * 4;
    const float4 v = reinterpret_cast<float4*>(xin)[i];
    const float4 hh = reinterpret_cast<const float4*>(h)[i];
    const float4 sc = *reinterpret_cast<const float4*>(&ss[c4]);
    const float4 sh = *reinterpret_cast<const float4*>(&ss[H + c4]);
    float4 o;
    o.x = (v.x * sc.x + sh.x + hh.x) * cinv + v.x;
    o.y = (v.y * sc.y + sh.y + hh.y) * cinv + v.y;
    o.z = (v.z * sc.z + sh.z + hh.z) * cinv + v.z;
    o.w = (v.w * sc.w + sh.w + hh.w) * cinv + v.w;
    reinterpret_cast<float4*>(xin)[i] = o;
  }
}

// ---------------------------------------------------------------- launch

extern "C" void kernel_launch(void* const* d_in, const int* in_sizes, int n_in,
                              void* d_out, int out_size, void* d_ws, size_t ws_size,
                              hipStream_t stream) {
  const int N = in_sizes[0] / 128;
  const int E = in_sizes[1] / 2;

  const float* x_vert = (const float*)d_in[0];
  const int* src = (const int*)d_in[1];
  const int* dst = src + E;
  const float* g1_lin_W = (const float*)d_in[2];
  const float* g1_lin_b = (const float*)d_in[3];
  const float* g1_c1_W = (const float*)d_in[4];
  const float* g1_c1_b = (const float*)d_in[5];
  const float* g1_c2_W = (const float*)d_in[6];
  const float* g1_c2_b = (const float*)d_in[7];
  const float* g1_n1_g = (const float*)d_in[8];
  const float* g1_n1_b = (const float*)d_in[9];
  const float* g1_n2_g = (const float*)d_in[10];
  const float* g1_n2_b = (const float*)d_in[11];
  const float* g2_lin_W = (const float*)d_in[12];
  const float* g2_lin_b = (const float*)d_in[13];
  const float* g2_c1_W = (const float*)d_in[14];
  const float* g2_c1_b = (const float*)d_in[15];
  const float* g2_c2_W = (const float*)d_in[16];
  const float* g2_c2_b = (const float*)d_in[17];
  const float* g2_n1_g = (const float*)d_in[18];
  const float* g2_n1_b = (const float*)d_in[19];
  const float* g2_n2_g = (const float*)d_in[20];
  const float* g2_n2_b = (const float*)d_in[21];
  const float* out_W = (const float*)d_in[22];
  const float* out_b = (const float*)d_in[23];
  const float* n1_g = (const float*)d_in[24];
  const float* n1_b = (const float*)d_in[25];
  const float* l1_W = (const float*)d_in[26];
  const float* l1_b = (const float*)d_in[27];
  const float* n2_g = (const float*)d_in[28];
  const float* n2_b = (const float*)d_in[29];
  const float* l2_W = (const float*)d_in[30];
  const float* l2_b = (const float*)d_in[31];

  float* out = (float*)d_out;

  // ---- workspace carve-up
  size_t off = 0;
  auto alloc = [&](size_t bytes) -> void* {
    void* p = (char*)d_ws + off;
    off += (bytes + 255) & ~(size_t)255;
    return p;
  };
  float* B1 = (float*)alloc((size_t)N * 256 * 4);
  float* B2 = (float*)alloc((size_t)N * 256 * 4);
  float* B3 = (float*)alloc((size_t)N * 256 * 4);
  int* cnt = (int*)alloc((size_t)N * 4);
  int* row_ptr = (int*)alloc((size_t)(N + 1) * 4);
  int* cursor = (int*)alloc((size_t)N * 4);
  int* col = (int*)alloc((size_t)E * 4);
  int* part = (int*)alloc(1024 * 4);
  float* dis = (float*)alloc((size_t)N * 4);
  float* sums = (float*)alloc(6 * 512 * 4);
  float* ssv = (float*)alloc(6 * 512 * 4);

  const int wk[9] = {128, 256, 256, 256, 128, 128, 128, 128, 64};
  const int wo[9] = {256, 256, 256, 128, 128, 128, 128, 64, 64};
  const float* wsrc[9] = {g1_lin_W, g1_c1_W, g1_c2_W, g2_lin_W, g2_c1_W,
                          g2_c2_W, out_W, l1_W, l2_W};
  ushort* whi[9];
  ushort* wlo[9];
  for (int i = 0; i < 9; ++i) {
    whi[i] = (ushort*)alloc((size_t)wk[i] * wo[i] * 2);
    wlo[i] = (ushort*)alloc((size_t)wk[i] * wo[i] * 2);
  }
  (void)ws_size;
  (void)n_in;
  (void)out_size;

  ushort* bb2 = (ushort*)B2;  // bf16 alias while B2-as-fp32 dead (block 1)
  ushort* bb3 = (ushort*)B3;  // bf16 alias while B3-as-fp32 dead (block 2)

  const int NB = IDIV(N, 256);
  const float invN = 1.0f / (float)N;

  // ---- CSR build + weight prep
  k_zero_i32<<<NB, 256, 0, stream>>>(cnt, N);
  k_zero_f32<<<IDIV(6 * 512, 256), 256, 0, stream>>>(sums, 6 * 512);
  {
    WPack p;
    for (int i = 0; i < 9; ++i) p.s[i] = WSpec{wsrc[i], whi[i], wlo[i], wk[i], wo[i]};
    k_wprep<<<dim3(64, 9), 256, 0, stream>>>(p);
  }
  k_count<<<IDIV(E, 256), 256, 0, stream>>>(dst, E, cnt);
  k_scan_partial<<<NB, 256, 0, stream>>>(cnt, N, part);
  k_scan_offsets<<<1, 256, 0, stream>>>(part, NB);
  k_scan_final<<<NB, 256, 0, stream>>>(cnt, N, part, row_ptr);
  k_cursor_dis<<<NB, 256, 0, stream>>>(row_ptr, cnt, cursor, dis, row_ptr + N, N, E);
  k_scatter<<<IDIV(E, 256), 256, 0, stream>>>(src, dst, E, cursor, col);

  const int GM = IDIV(N, 128);
  float* ss0 = ssv + 0 * 512;
  float* ss1 = ssv + 1 * 512;
  float* ss2 = ssv + 2 * 512;
  float* ss3 = ssv + 3 * 512;
  float* ss4 = ssv + 4 * 512;
  float* ss5 = ssv + 5 * 512;

  // ================= block 1 (in 128, hid 256) =================
  k_gemm_mfma<128, 256, false, true, false>
      <<<dim3(GM, 2), 256, 0, stream>>>(x_vert, whi[0], wlo[0], g1_lin_b, nullptr, B1, N);
  k_colstats<256><<<NB, 256, 0, stream>>>(B1, N, sums + 0 * 512);
  k_bnfin<<<1, 256, 0, stream>>>(sums + 0 * 512, g1_n1_g, g1_n1_b, ss0, 256, invN);
  k_gemm_mfma<256, 256, true, false, true>
      <<<dim3(GM, 2), 256, 0, stream>>>(B1, whi[1], wlo[1], nullptr, ss0, bb2, N);
  k_agg_bf<256><<<IDIV(N, 4), 256, 0, stream>>>(bb2, row_ptr, col, dis, g1_c1_b, B3, N);
  k_colstats<256><<<NB, 256, 0, stream>>>(B3, N, sums + 1 * 512);
  k_bnfin<<<1, 256, 0, stream>>>(sums + 1 * 512, g1_n2_g, g1_n2_b, ss1, 256, invN);
  k_gemm_mfma<256, 256, true, false, true>
      <<<dim3(GM, 2), 256, 0, stream>>>(B3, whi[2], wlo[2], nullptr, ss1, bb2, N);
  k_agg_bf<256><<<IDIV(N, 4), 256, 0, stream>>>(bb2, row_ptr, col, dis, g1_c2_b, B3, N);
  k_combine4<256><<<IDIV(N * 64, 256), 256, 0, stream>>>(B1, B3, ss0, N * 64);

  // ================= block 2 (in 256, hid 128) =================
  k_gemm_mfma<256, 128, false, true, false>
      <<<dim3(GM, 1), 256, 0, stream>>>(B1, whi[3], wlo[3], g2_lin_b, nullptr, B2, N);
  k_colstats<128><<<NB, 256, 0, stream>>>(B2, N, sums + 2 * 512);
  k_bnfin<<<1, 256, 0, stream>>>(sums + 2 * 512, g2_n1_g, g2_n1_b, ss2, 128, invN);
  k_gemm_mfma<128, 128, true, false, true>
      <<<dim3(GM, 1), 256, 0, stream>>>(B2, whi[4], wlo[4], nullptr, ss2, bb3, N);
  k_agg_bf<128><<<IDIV(N, 4), 256, 0, stream>>>(bb3, row_ptr, col, dis, g2_c1_b, B1, N);
  k_colstats<128><<<NB, 256, 0, stream>>>(B1, N, sums + 3 * 512);
  k_bnfin<<<1, 256, 0, stream>>>(sums + 3 * 512, g2_n2_g, g2_n2_b, ss3, 128, invN);
  k_gemm_mfma<128, 128, true, false, true>
      <<<dim3(GM, 1), 256, 0, stream>>>(B1, whi[5], wlo[5], nullptr, ss3, bb3, N);
  k_agg_bf<128><<<IDIV(N, 4), 256, 0, stream>>>(bb3, row_ptr, col, dis, g2_c2_b, B1, N);
  k_combine4<128><<<IDIV(N * 32, 256), 256, 0, stream>>>(B2, B1, ss2, N * 32);

  // ================= head =================
  k_gemm_mfma<128, 128, false, true, false>
      <<<dim3(GM, 1), 256, 0, stream>>>(B2, whi[6], wlo[6], out_b, nullptr, B1, N);
  k_colstats<128><<<NB, 256, 0, stream>>>(B1, N, sums + 4 * 512);
  k_bnfin<<<1, 256, 0, stream>>>(sums + 4 * 512, n1_g, n1_b, ss4, 128, invN);
  k_gemm_mfma<128, 64, true, true, false>
      <<<dim3(GM, 1), 256, 0, stream>>>(B1, whi[7], wlo[7], l1_b, ss4, B3, N);
  k_colstats<64><<<NB, 256, 0, stream>>>(B3, N, sums + 5 * 512);
  k_bnfin<<<1, 256, 0, stream>>>(sums + 5 * 512, n2_g, n2_b, ss5, 64, invN);
  k_gemm_mfma<64, 64, true, true, false>
      <<<dim3(GM, 1), 256, 0, stream>>>(B3, whi[8], wlo[8], l2_b, ss5, out, N);
}

// Round 4
// 775.713 us; speedup vs baseline: 1.6325x; 1.0735x over previous
//
#include <hip/hip_runtime.h>
#include <cstddef>
#include <cstdint>

#define IDIV(a, b) (((a) + (b) - 1) / (b))

typedef __attribute__((ext_vector_type(8))) short short8;
typedef __attribute__((ext_vector_type(8))) unsigned short ushort8v;
typedef __attribute__((ext_vector_type(4))) float f32x4;

__device__ inline ushort f2bf_rne(float x) {
  uint32_t u = __builtin_bit_cast(uint32_t, x);
  u += 0x7fff + ((u >> 16) & 1);
  return (ushort)(u >> 16);
}
__device__ inline float bf2f(ushort h) {
  uint32_t u = (uint32_t)h << 16;
  return __builtin_bit_cast(float, u);
}

// ---------------------------------------------------------------- utilities

__global__ void k_zero_i32(int* __restrict__ p, int n) {
  int i = blockIdx.x * blockDim.x + threadIdx.x;
  if (i < n) p[i] = 0;
}

__global__ void k_zero_f32(float* __restrict__ p, int n) {
  int i = blockIdx.x * blockDim.x + threadIdx.x;
  if (i < n) p[i] = 0.f;
}

// ---------------------------------------------------------------- CSR build

__global__ void k_count(const int* __restrict__ dst, int E, int* __restrict__ cnt) {
  int i = blockIdx.x * blockDim.x + threadIdx.x;
  if (i < E) atomicAdd(&cnt[dst[i]], 1);
}

__global__ void k_scan_partial(const int* __restrict__ cnt, int n, int* __restrict__ part) {
  __shared__ int sm[256];
  const int t = threadIdx.x;
  const int i = blockIdx.x * 256 + t;
  sm[t] = (i < n) ? cnt[i] : 0;
  __syncthreads();
  for (int off = 128; off > 0; off >>= 1) {
    if (t < off) sm[t] += sm[t + off];
    __syncthreads();
  }
  if (t == 0) part[blockIdx.x] = sm[0];
}

__global__ void k_scan_offsets(int* __restrict__ part, int nb) {
  __shared__ int sm[256];
  const int t = threadIdx.x;
  if (t < nb) sm[t] = part[t];
  __syncthreads();
  if (t == 0) {
    int run = 0;
    for (int i = 0; i < nb; ++i) { int v = sm[i]; sm[i] = run; run += v; }
  }
  __syncthreads();
  if (t < nb) part[t] = sm[t];
}

__global__ void k_scan_final(const int* __restrict__ cnt, int n, const int* __restrict__ part,
                             int* __restrict__ row_ptr) {
  __shared__ int sm[256];
  const int t = threadIdx.x;
  const int i = blockIdx.x * 256 + t;
  const int v = (i < n) ? cnt[i] : 0;
  sm[t] = v;
  __syncthreads();
  for (int off = 1; off < 256; off <<= 1) {
    int x = (t >= off) ? sm[t - off] : 0;
    __syncthreads();
    sm[t] += x;
    __syncthreads();
  }
  if (i < n) row_ptr[i] = part[blockIdx.x] + sm[t] - v;  // exclusive scan
}

__global__ void k_cursor_dis(const int* __restrict__ row_ptr, const int* __restrict__ cnt,
                             int* __restrict__ cursor, float* __restrict__ dis,
                             int* __restrict__ row_ptr_end, int n, int E) {
  int i = blockIdx.x * blockDim.x + threadIdx.x;
  if (i == 0) *row_ptr_end = E;
  if (i < n) {
    cursor[i] = row_ptr[i];
    dis[i] = rsqrtf((float)cnt[i] + 1.0f);
  }
}

__global__ void k_scatter(const int* __restrict__ src, const int* __restrict__ dst, int E,
                          int* __restrict__ cursor, int* __restrict__ col) {
  int i = blockIdx.x * blockDim.x + threadIdx.x;
  if (i < E) {
    int d = dst[i];
    int pos = atomicAdd(&cursor[d], 1);
    col[pos] = src[i];
  }
}

// ---------------------------------------------------------------- weight prep
// W[K][O] fp32 -> Wt_hi[O][K], Wt_lo[O][K] bf16 (transposed + hi/lo split)

struct WSpec { const float* W; ushort* hi; ushort* lo; int K; int O; };
struct WPack { WSpec s[9]; };

__global__ void k_wprep(WPack p) {
  const WSpec w = p.s[blockIdx.y];
  const int total = w.K * w.O;
  for (int i = blockIdx.x * 256 + threadIdx.x; i < total; i += gridDim.x * 256) {
    const int o = i / w.K;
    const int k = i - o * w.K;
    const float v = w.W[(size_t)k * w.O + o];
    const ushort h = f2bf_rne(v);
    w.hi[i] = h;
    w.lo[i] = f2bf_rne(v - bf2f(h));
  }
}

// ---------------------------------------------------------------- MFMA GEMM
// C[N,O] = op(A)[N,K] @ W[K,O] (+ bias); op = PRO ? lrelu(A*sc+sh) : A
// A in bf16-hi (plus lo-plane when ASPLIT); W pre-split bf16 hi+lo.
// LDS layout fragment-blocked: As[buf][plane][rowblk][kgrp][16 rows][8 k]
// -> each wave ds_read_b128 covers a contiguous 1KB (conflict-free).
// B register double-buffered across k-steps; k-loop unrolled x2 so all
// buffer indices are compile-time (no scratch).

template <int K, int O, bool PRO, bool BIAS, bool OUTBF, bool ASPLIT>
__launch_bounds__(256, 2)
__global__ void k_gemm_mfma(const float* __restrict__ A, const ushort* __restrict__ Whi,
                            const ushort* __restrict__ Wlo, const float* __restrict__ bias,
                            const float* __restrict__ ss, void* __restrict__ Cout, int N) {
  constexpr int BN = (O >= 128) ? 128 : O;  // 128 or 64
  constexpr int KS = K / 32;                // k-steps (even for all our K)
  constexpr int WC = (BN == 128) ? 2 : 1;
  constexpr int WR = 4 / WC;
  constexpr int MF = (128 / WR) / 16;
  constexpr int NF = 4;
  constexpr int PL = ASPLIT ? 2 : 1;

  __shared__ __align__(16) ushort As[2][PL][8][4][16][8];

  const int bm = blockIdx.x * 128;
  const int bo = blockIdx.y * BN;
  const int t = threadIdx.x;
  const int w = t >> 6, l = t & 63;
  const int wr = w / WC, wc = w % WC;
  const int r0 = wr * (128 / WR);
  const int c0 = wc * 64;
  const int lr = l & 15;        // fragment row lane index
  const int lks = l >> 4;       // fragment k-group (8 bf16 each)
  const int lk = lks * 8;

  // A staging: thread t covers row ar = t>>1, two k-groups g0,g0+1
  const int ar = t >> 1;
  const int g0 = (t & 1) * 2;
  const int arow = bm + ar;

  f32x4 acc[MF][NF];
  const f32x4 zero4 = {0.f, 0.f, 0.f, 0.f};
#pragma unroll
  for (int mf = 0; mf < MF; ++mf)
#pragma unroll
    for (int nf = 0; nf < NF; ++nf) acc[mf][nf] = zero4;

  auto loadA = [&](int ks, float4 v[4]) {
    if (arow < N) {
#pragma unroll
      for (int q = 0; q < 4; ++q)
        v[q] = *reinterpret_cast<const float4*>(&A[(size_t)arow * K + ks * 32 + g0 * 8 + q * 4]);
    } else {
#pragma unroll
      for (int q = 0; q < 4; ++q) v[q] = make_float4(0.f, 0.f, 0.f, 0.f);
    }
  };

  auto stageA = [&](int buf, int ks, float4 v[4]) {
    if (PRO) {
#pragma unroll
      for (int q = 0; q < 4; ++q) {
        const float4 sc = *reinterpret_cast<const float4*>(&ss[ks * 32 + g0 * 8 + q * 4]);
        const float4 sh = *reinterpret_cast<const float4*>(&ss[K + ks * 32 + g0 * 8 + q * 4]);
        float4& x = v[q];
        x.x = x.x * sc.x + sh.x; x.x = x.x > 0.f ? x.x : 0.01f * x.x;
        x.y = x.y * sc.y + sh.y; x.y = x.y > 0.f ? x.y : 0.01f * x.y;
        x.z = x.z * sc.z + sh.z; x.z = x.z > 0.f ? x.z : 0.01f * x.z;
        x.w = x.w * sc.w + sh.w; x.w = x.w > 0.f ? x.w : 0.01f * x.w;
      }
    }
    const float f[16] = {v[0].x, v[0].y, v[0].z, v[0].w, v[1].x, v[1].y, v[1].z, v[1].w,
                         v[2].x, v[2].y, v[2].z, v[2].w, v[3].x, v[3].y, v[3].z, v[3].w};
    ushort8v h0, h1;
#pragma unroll
    for (int j = 0; j < 8; ++j) { h0[j] = f2bf_rne(f[j]); h1[j] = f2bf_rne(f[8 + j]); }
    *reinterpret_cast<ushort8v*>(&As[buf][0][ar >> 4][g0][ar & 15][0]) = h0;
    *reinterpret_cast<ushort8v*>(&As[buf][0][ar >> 4][g0 + 1][ar & 15][0]) = h1;
    if (ASPLIT) {
      ushort8v l0, l1;
#pragma unroll
      for (int j = 0; j < 8; ++j) {
        l0[j] = f2bf_rne(f[j] - bf2f(h0[j]));
        l1[j] = f2bf_rne(f[8 + j] - bf2f(h1[j]));
      }
      *reinterpret_cast<ushort8v*>(&As[buf][PL - 1][ar >> 4][g0][ar & 15][0]) = l0;
      *reinterpret_cast<ushort8v*>(&As[buf][PL - 1][ar >> 4][g0 + 1][ar & 15][0]) = l1;
    }
  };

  auto loadB = [&](int ks, short8 (&bh)[NF], short8 (&bl)[NF]) {
#pragma unroll
    for (int nf = 0; nf < NF; ++nf) {
      const size_t boff = (size_t)(bo + c0 + nf * 16 + lr) * K + ks * 32 + lk;
      bh[nf] = *reinterpret_cast<const short8*>(&Whi[boff]);
      bl[nf] = *reinterpret_cast<const short8*>(&Wlo[boff]);
    }
  };

  auto mmstep = [&](int buf, short8 (&bh)[NF], short8 (&bl)[NF]) {
#pragma unroll
    for (int mf = 0; mf < MF; ++mf) {
      const int rb = (r0 >> 4) + mf;
      const short8 ah = *reinterpret_cast<const short8*>(&As[buf][0][rb][lks][lr][0]);
#pragma unroll
      for (int nf = 0; nf < NF; ++nf) {
        acc[mf][nf] = __builtin_amdgcn_mfma_f32_16x16x32_bf16(ah, bh[nf], acc[mf][nf], 0, 0, 0);
        acc[mf][nf] = __builtin_amdgcn_mfma_f32_16x16x32_bf16(ah, bl[nf], acc[mf][nf], 0, 0, 0);
      }
      if (ASPLIT) {
        const short8 al = *reinterpret_cast<const short8*>(&As[buf][PL - 1][rb][lks][lr][0]);
#pragma unroll
        for (int nf = 0; nf < NF; ++nf)
          acc[mf][nf] = __builtin_amdgcn_mfma_f32_16x16x32_bf16(al, bh[nf], acc[mf][nf], 0, 0, 0);
      }
    }
  };

  float4 v0[4], v1[4];
  short8 bhA[NF], blA[NF], bhB[NF], blB[NF];

  loadA(0, v0);
  stageA(0, 0, v0);
  loadB(0, bhA, blA);
  __syncthreads();

  for (int ks = 0; ks < KS; ks += 2) {
    // even step: LDS buf 0, B regs A; prefetch ks+1
    loadA(ks + 1, v1);
    loadB(ks + 1, bhB, blB);
    mmstep(0, bhA, blA);
    stageA(1, ks + 1, v1);
    __syncthreads();
    // odd step: LDS buf 1, B regs B; prefetch ks+2
    const bool more = (ks + 2) < KS;
    if (more) {
      loadA(ks + 2, v0);
      loadB(ks + 2, bhA, blA);
    }
    mmstep(1, bhB, blB);
    if (more) stageA(0, ks + 2, v0);
    __syncthreads();
  }

  // epilogue: C[row = bm+r0+mf*16+(l>>4)*4+rg][col = bo+c0+nf*16+lr]
#pragma unroll
  for (int mf = 0; mf < MF; ++mf) {
    const int gr0 = bm + r0 + mf * 16 + (l >> 4) * 4;
#pragma unroll
    for (int nf = 0; nf < NF; ++nf) {
      const int gc = bo + c0 + nf * 16 + lr;
      float bval = 0.f;
      if (BIAS) bval = bias[gc];
#pragma unroll
      for (int rg = 0; rg < 4; ++rg) {
        const int row = gr0 + rg;
        if (row < N) {
          const float v = acc[mf][nf][rg] + bval;
          if (OUTBF)
            ((ushort*)Cout)[(size_t)row * O + gc] = f2bf_rne(v);
          else
            ((float*)Cout)[(size_t)row * O + gc] = v;
        }
      }
    }
  }
}

// ---------------------------------------------------------------- BN column stats

template <int H>
__launch_bounds__(256)
__global__ void k_colstats(const float* __restrict__ X, int n, float* __restrict__ sums) {
  constexpr int G = H / 4;      // column groups of 4
  constexpr int NS = 256 / G;   // row subgroups
  const int t = threadIdx.x;
  const int cg = t % G;
  const int sub = t / G;
  const int r0 = blockIdx.x * 256;
  const int rend = (r0 + 256 < n) ? r0 + 256 : n;
  float4 s = make_float4(0.f, 0.f, 0.f, 0.f);
  float4 s2 = make_float4(0.f, 0.f, 0.f, 0.f);
  for (int r = r0 + sub; r < rend; r += NS) {
    const float4 v = *reinterpret_cast<const float4*>(&X[(size_t)r * H + cg * 4]);
    s.x += v.x; s.y += v.y; s.z += v.z; s.w += v.w;
    s2.x += v.x * v.x; s2.y += v.y * v.y; s2.z += v.z * v.z; s2.w += v.w * v.w;
  }
  __shared__ float red[256][8];
  red[t][0] = s.x; red[t][1] = s.y; red[t][2] = s.z; red[t][3] = s.w;
  red[t][4] = s2.x; red[t][5] = s2.y; red[t][6] = s2.z; red[t][7] = s2.w;
  __syncthreads();
  if (sub == 0) {
#pragma unroll
    for (int k = 1; k < NS; ++k) {
      const int u = cg + k * G;
      s.x += red[u][0]; s.y += red[u][1]; s.z += red[u][2]; s.w += red[u][3];
      s2.x += red[u][4]; s2.y += red[u][5]; s2.z += red[u][6]; s2.w += red[u][7];
    }
    atomicAdd(&sums[cg * 4 + 0], s.x);
    atomicAdd(&sums[cg * 4 + 1], s.y);
    atomicAdd(&sums[cg * 4 + 2], s.z);
    atomicAdd(&sums[cg * 4 + 3], s.w);
    atomicAdd(&sums[H + cg * 4 + 0], s2.x);
    atomicAdd(&sums[H + cg * 4 + 1], s2.y);
    atomicAdd(&sums[H + cg * 4 + 2], s2.z);
    atomicAdd(&sums[H + cg * 4 + 3], s2.w);
  }
}

__global__ void k_bnfin(const float* __restrict__ sums, const float* __restrict__ g,
                        const float* __restrict__ b, float* __restrict__ ss, int H, float invN) {
  const int c = threadIdx.x;
  if (c < H) {
    const float mean = sums[c] * invN;
    float var = sums[H + c] * invN - mean * mean;
    var = var < 0.f ? 0.f : var;
    const float sc = g[c] * rsqrtf(var + 1e-5f);
    ss[c] = sc;
    ss[H + c] = b[c] - mean * sc;
  }
}

// ---------------------------------------------------------------- GCN aggregation (bf16 in)
// out[d] = sum_{e:(s->d)} Hin[s]*dis[s]*dis[d] + Hin[d]*dis[d]^2 + bias
// 8-wide batched edge loop (clamped tail) -> 8 outstanding gather chains.

template <int H>
__launch_bounds__(256)
__global__ void k_agg_bf(const ushort* __restrict__ Hin, const int* __restrict__ row_ptr,
                         const int* __restrict__ col, const float* __restrict__ dis,
                         const float* __restrict__ bias, float* __restrict__ out, int n) {
  constexpr int V = H / 64;
  const int lane = threadIdx.x & 63;
  const int node = blockIdx.x * 4 + (threadIdx.x >> 6);
  if (node >= n) return;
  const int beg = row_ptr[node];
  const int end = row_ptr[node + 1];
  const float dd = dis[node];
  const int lv = lane * V;
  float acc[V];
#pragma unroll
  for (int j = 0; j < V; ++j) acc[j] = 0.f;

  for (int e = beg; e < end; e += 8) {
    int s[8];
    float w[8];
#pragma unroll
    for (int i = 0; i < 8; ++i) {
      const bool valid = (e + i) < end;
      s[i] = col[valid ? e + i : end - 1];
      w[i] = valid ? dd : 0.f;
    }
#pragma unroll
    for (int i = 0; i < 8; ++i) w[i] *= dis[s[i]];
    if constexpr (V == 4) {
      ushort4 u[8];
#pragma unroll
      for (int i = 0; i < 8; ++i)
        u[i] = *reinterpret_cast<const ushort4*>(&Hin[(size_t)s[i] * H + lv]);
#pragma unroll
      for (int i = 0; i < 8; ++i) {
        acc[0] += bf2f(u[i].x) * w[i];
        acc[1] += bf2f(u[i].y) * w[i];
        acc[2] += bf2f(u[i].z) * w[i];
        acc[3] += bf2f(u[i].w) * w[i];
      }
    } else {
      ushort2 u[8];
#pragma unroll
      for (int i = 0; i < 8; ++i)
        u[i] = *reinterpret_cast<const ushort2*>(&Hin[(size_t)s[i] * H + lv]);
#pragma unroll
      for (int i = 0; i < 8; ++i) {
        acc[0] += bf2f(u[i].x) * w[i];
        acc[1] += bf2f(u[i].y) * w[i];
      }
    }
  }

  const float sw = dd * dd;
  if constexpr (V == 4) {
    const ushort4 u = *reinterpret_cast<const ushort4*>(&Hin[(size_t)node * H + lv]);
    acc[0] += bf2f(u.x) * sw; acc[1] += bf2f(u.y) * sw;
    acc[2] += bf2f(u.z) * sw; acc[3] += bf2f(u.w) * sw;
    const float4 bv = *reinterpret_cast<const float4*>(&bias[lv]);
    float4 o;
    o.x = acc[0] + bv.x; o.y = acc[1] + bv.y; o.z = acc[2] + bv.z; o.w = acc[3] + bv.w;
    *reinterpret_cast<float4*>(&out[(size_t)node * H + lv]) = o;
  } else {
    const ushort2 u = *reinterpret_cast<const ushort2*>(&Hin[(size_t)node * H + lv]);
    acc[0] += bf2f(u.x) * sw; acc[1] += bf2f(u.y) * sw;
    const float2 bv = *reinterpret_cast<const float2*>(&bias[lv]);
    float2 o;
    o.x = acc[0] + bv.x; o.y = acc[1] + bv.y;
    *reinterpret_cast<float2*>(&out[(size_t)node * H + lv]) = o;
  }
}

// ---------------------------------------------------------------- residual combine
// xin = (BN(xin) + h) * 2^-0.5 + xin   (float4 per thread)

template <int H>
__global__ void k_combine4(float* __restrict__ xin, const float* __restrict__ h,
                           const float* __restrict__ ss, int total4) {
  const float cinv = 0.70710678118654752f;
  int i = blockIdx.x * blockDim.x + threadIdx.x;
  if (i < total4) {
    const int c4 = (i & (H / 4 - 1)) * 4;
    const float4 v = reinterpret_cast<float4*>(xin)[i];
    const float4 hh = reinterpret_cast<const float4*>(h)[i];
    const float4 sc = *reinterpret_cast<const float4*>(&ss[c4]);
    const float4 sh = *reinterpret_cast<const float4*>(&ss[H + c4]);
    float4 o;
    o.x = (v.x * sc.x + sh.x + hh.x) * cinv + v.x;
    o.y = (v.y * sc.y + sh.y + hh.y) * cinv + v.y;
    o.z = (v.z * sc.z + sh.z + hh.z) * cinv + v.z;
    o.w = (v.w * sc.w + sh.w + hh.w) * cinv + v.w;
    reinterpret_cast<float4*>(xin)[i] = o;
  }
}

// ---------------------------------------------------------------- launch

extern "C" void kernel_launch(void* const* d_in, const int* in_sizes, int n_in,
                              void* d_out, int out_size, void* d_ws, size_t ws_size,
                              hipStream_t stream) {
  const int N = in_sizes[0] / 128;
  const int E = in_sizes[1] / 2;

  const float* x_vert = (const float*)d_in[0];
  const int* src = (const int*)d_in[1];
  const int* dst = src + E;
  const float* g1_lin_W = (const float*)d_in[2];
  const float* g1_lin_b = (const float*)d_in[3];
  const float* g1_c1_W = (const float*)d_in[4];
  const float* g1_c1_b = (const float*)d_in[5];
  const float* g1_c2_W = (const float*)d_in[6];
  const float* g1_c2_b = (const float*)d_in[7];
  const float* g1_n1_g = (const float*)d_in[8];
  const float* g1_n1_b = (const float*)d_in[9];
  const float* g1_n2_g = (const float*)d_in[10];
  const float* g1_n2_b = (const float*)d_in[11];
  const float* g2_lin_W = (const float*)d_in[12];
  const float* g2_lin_b = (const float*)d_in[13];
  const float* g2_c1_W = (const float*)d_in[14];
  const float* g2_c1_b = (const float*)d_in[15];
  const float* g2_c2_W = (const float*)d_in[16];
  const float* g2_c2_b = (const float*)d_in[17];
  const float* g2_n1_g = (const float*)d_in[18];
  const float* g2_n1_b = (const float*)d_in[19];
  const float* g2_n2_g = (const float*)d_in[20];
  const float* g2_n2_b = (const float*)d_in[21];
  const float* out_W = (const float*)d_in[22];
  const float* out_b = (const float*)d_in[23];
  const float* n1_g = (const float*)d_in[24];
  const float* n1_b = (const float*)d_in[25];
  const float* l1_W = (const float*)d_in[26];
  const float* l1_b = (const float*)d_in[27];
  const float* n2_g = (const float*)d_in[28];
  const float* n2_b = (const float*)d_in[29];
  const float* l2_W = (const float*)d_in[30];
  const float* l2_b = (const float*)d_in[31];

  float* out = (float*)d_out;

  // ---- workspace carve-up
  size_t off = 0;
  auto alloc = [&](size_t bytes) -> void* {
    void* p = (char*)d_ws + off;
    off += (bytes + 255) & ~(size_t)255;
    return p;
  };
  float* B1 = (float*)alloc((size_t)N * 256 * 4);
  float* B2 = (float*)alloc((size_t)N * 256 * 4);
  float* B3 = (float*)alloc((size_t)N * 256 * 4);
  int* cnt = (int*)alloc((size_t)N * 4);
  int* row_ptr = (int*)alloc((size_t)(N + 1) * 4);
  int* cursor = (int*)alloc((size_t)N * 4);
  int* col = (int*)alloc((size_t)E * 4);
  int* part = (int*)alloc(1024 * 4);
  float* dis = (float*)alloc((size_t)N * 4);
  float* sums = (float*)alloc(6 * 512 * 4);
  float* ssv = (float*)alloc(6 * 512 * 4);

  const int wk[9] = {128, 256, 256, 256, 128, 128, 128, 128, 64};
  const int wo[9] = {256, 256, 256, 128, 128, 128, 128, 64, 64};
  const float* wsrc[9] = {g1_lin_W, g1_c1_W, g1_c2_W, g2_lin_W, g2_c1_W,
                          g2_c2_W, out_W, l1_W, l2_W};
  ushort* whi[9];
  ushort* wlo[9];
  for (int i = 0; i < 9; ++i) {
    whi[i] = (ushort*)alloc((size_t)wk[i] * wo[i] * 2);
    wlo[i] = (ushort*)alloc((size_t)wk[i] * wo[i] * 2);
  }
  (void)ws_size;
  (void)n_in;
  (void)out_size;

  ushort* bb2 = (ushort*)B2;  // bf16 alias while B2-as-fp32 dead (block 1)
  ushort* bb3 = (ushort*)B3;  // bf16 alias while B3-as-fp32 dead (block 2)

  const int NB = IDIV(N, 256);
  const float invN = 1.0f / (float)N;

  // ---- CSR build + weight prep
  k_zero_i32<<<NB, 256, 0, stream>>>(cnt, N);
  k_zero_f32<<<IDIV(6 * 512, 256), 256, 0, stream>>>(sums, 6 * 512);
  {
    WPack p;
    for (int i = 0; i < 9; ++i) p.s[i] = WSpec{wsrc[i], whi[i], wlo[i], wk[i], wo[i]};
    k_wprep<<<dim3(64, 9), 256, 0, stream>>>(p);
  }
  k_count<<<IDIV(E, 256), 256, 0, stream>>>(dst, E, cnt);
  k_scan_partial<<<NB, 256, 0, stream>>>(cnt, N, part);
  k_scan_offsets<<<1, 256, 0, stream>>>(part, NB);
  k_scan_final<<<NB, 256, 0, stream>>>(cnt, N, part, row_ptr);
  k_cursor_dis<<<NB, 256, 0, stream>>>(row_ptr, cnt, cursor, dis, row_ptr + N, N, E);
  k_scatter<<<IDIV(E, 256), 256, 0, stream>>>(src, dst, E, cursor, col);

  const int GM = IDIV(N, 128);
  float* ss0 = ssv + 0 * 512;
  float* ss1 = ssv + 1 * 512;
  float* ss2 = ssv + 2 * 512;
  float* ss3 = ssv + 3 * 512;
  float* ss4 = ssv + 4 * 512;
  float* ss5 = ssv + 5 * 512;

  // ================= block 1 (in 128, hid 256) =================
  k_gemm_mfma<128, 256, false, true, false, false>
      <<<dim3(GM, 2), 256, 0, stream>>>(x_vert, whi[0], wlo[0], g1_lin_b, nullptr, B1, N);
  k_colstats<256><<<NB, 256, 0, stream>>>(B1, N, sums + 0 * 512);
  k_bnfin<<<1, 256, 0, stream>>>(sums + 0 * 512, g1_n1_g, g1_n1_b, ss0, 256, invN);
  k_gemm_mfma<256, 256, true, false, true, false>
      <<<dim3(GM, 2), 256, 0, stream>>>(B1, whi[1], wlo[1], nullptr, ss0, bb2, N);
  k_agg_bf<256><<<IDIV(N, 4), 256, 0, stream>>>(bb2, row_ptr, col, dis, g1_c1_b, B3, N);
  k_colstats<256><<<NB, 256, 0, stream>>>(B3, N, sums + 1 * 512);
  k_bnfin<<<1, 256, 0, stream>>>(sums + 1 * 512, g1_n2_g, g1_n2_b, ss1, 256, invN);
  k_gemm_mfma<256, 256, true, false, true, false>
      <<<dim3(GM, 2), 256, 0, stream>>>(B3, whi[2], wlo[2], nullptr, ss1, bb2, N);
  k_agg_bf<256><<<IDIV(N, 4), 256, 0, stream>>>(bb2, row_ptr, col, dis, g1_c2_b, B3, N);
  k_combine4<256><<<IDIV(N * 64, 256), 256, 0, stream>>>(B1, B3, ss0, N * 64);

  // ================= block 2 (in 256, hid 128) =================
  k_gemm_mfma<256, 128, false, true, false, false>
      <<<dim3(GM, 1), 256, 0, stream>>>(B1, whi[3], wlo[3], g2_lin_b, nullptr, B2, N);
  k_colstats<128><<<NB, 256, 0, stream>>>(B2, N, sums + 2 * 512);
  k_bnfin<<<1, 256, 0, stream>>>(sums + 2 * 512, g2_n1_g, g2_n1_b, ss2, 128, invN);
  k_gemm_mfma<128, 128, true, false, true, false>
      <<<dim3(GM, 1), 256, 0, stream>>>(B2, whi[4], wlo[4], nullptr, ss2, bb3, N);
  k_agg_bf<128><<<IDIV(N, 4), 256, 0, stream>>>(bb3, row_ptr, col, dis, g2_c1_b, B1, N);
  k_colstats<128><<<NB, 256, 0, stream>>>(B1, N, sums + 3 * 512);
  k_bnfin<<<1, 256, 0, stream>>>(sums + 3 * 512, g2_n2_g, g2_n2_b, ss3, 128, invN);
  k_gemm_mfma<128, 128, true, false, true, false>
      <<<dim3(GM, 1), 256, 0, stream>>>(B1, whi[5], wlo[5], nullptr, ss3, bb3, N);
  k_agg_bf<128><<<IDIV(N, 4), 256, 0, stream>>>(bb3, row_ptr, col, dis, g2_c2_b, B1, N);
  k_combine4<128><<<IDIV(N * 32, 256), 256, 0, stream>>>(B2, B1, ss2, N * 32);

  // ================= head =================
  k_gemm_mfma<128, 128, false, true, false, false>
      <<<dim3(GM, 1), 256, 0, stream>>>(B2, whi[6], wlo[6], out_b, nullptr, B1, N);
  k_colstats<128><<<NB, 256, 0, stream>>>(B1, N, sums + 4 * 512);
  k_bnfin<<<1, 256, 0, stream>>>(sums + 4 * 512, n1_g, n1_b, ss4, 128, invN);
  k_gemm_mfma<128, 64, true, true, false, true>
      <<<dim3(GM, 1), 256, 0, stream>>>(B1, whi[7], wlo[7], l1_b, ss4, B3, N);
  k_colstats<64><<<NB, 256, 0, stream>>>(B3, N, sums + 5 * 512);
  k_bnfin<<<1, 256, 0, stream>>>(sums + 5 * 512, n2_g, n2_b, ss5, 64, invN);
  k_gemm_mfma<64, 64, true, true, false, true>
      <<<dim3(GM, 1), 256, 0, stream>>>(B3, whi[8], wlo[8], l2_b, ss5, out, N);
}

// Round 5
// 744.665 us; speedup vs baseline: 1.7006x; 1.0417x over previous
//
#include <hip/hip_runtime.h>
#include <cstddef>
#include <cstdint>

#define IDIV(a, b) (((a) + (b) - 1) / (b))

typedef __attribute__((ext_vector_type(8))) short short8;
typedef __attribute__((ext_vector_type(8))) unsigned short ushort8v;
typedef __attribute__((ext_vector_type(4))) float f32x4;

__device__ inline ushort f2bf_rne(float x) {
  uint32_t u = __builtin_bit_cast(uint32_t, x);
  u += 0x7fff + ((u >> 16) & 1);
  return (ushort)(u >> 16);
}
__device__ inline float bf2f(ushort h) {
  uint32_t u = (uint32_t)h << 16;
  return __builtin_bit_cast(float, u);
}

// ---------------------------------------------------------------- utilities

__global__ void k_zero_i32(int* __restrict__ p, int n) {
  int i = blockIdx.x * blockDim.x + threadIdx.x;
  if (i < n) p[i] = 0;
}

__global__ void k_zero_f32(float* __restrict__ p, int n) {
  int i = blockIdx.x * blockDim.x + threadIdx.x;
  if (i < n) p[i] = 0.f;
}

// ---------------------------------------------------------------- CSR build

__global__ void k_count(const int* __restrict__ dst, int E, int* __restrict__ cnt) {
  int i = blockIdx.x * blockDim.x + threadIdx.x;
  if (i < E) atomicAdd(&cnt[dst[i]], 1);
}

__global__ void k_scan_partial(const int* __restrict__ cnt, int n, int* __restrict__ part) {
  __shared__ int sm[256];
  const int t = threadIdx.x;
  const int i = blockIdx.x * 256 + t;
  sm[t] = (i < n) ? cnt[i] : 0;
  __syncthreads();
  for (int off = 128; off > 0; off >>= 1) {
    if (t < off) sm[t] += sm[t + off];
    __syncthreads();
  }
  if (t == 0) part[blockIdx.x] = sm[0];
}

__global__ void k_scan_offsets(int* __restrict__ part, int nb) {
  __shared__ int sm[256];
  const int t = threadIdx.x;
  if (t < nb) sm[t] = part[t];
  __syncthreads();
  if (t == 0) {
    int run = 0;
    for (int i = 0; i < nb; ++i) { int v = sm[i]; sm[i] = run; run += v; }
  }
  __syncthreads();
  if (t < nb) part[t] = sm[t];
}

__global__ void k_scan_final(const int* __restrict__ cnt, int n, const int* __restrict__ part,
                             int* __restrict__ row_ptr) {
  __shared__ int sm[256];
  const int t = threadIdx.x;
  const int i = blockIdx.x * 256 + t;
  const int v = (i < n) ? cnt[i] : 0;
  sm[t] = v;
  __syncthreads();
  for (int off = 1; off < 256; off <<= 1) {
    int x = (t >= off) ? sm[t - off] : 0;
    __syncthreads();
    sm[t] += x;
    __syncthreads();
  }
  if (i < n) row_ptr[i] = part[blockIdx.x] + sm[t] - v;  // exclusive scan
}

__global__ void k_cursor_dis(const int* __restrict__ row_ptr, const int* __restrict__ cnt,
                             int* __restrict__ cursor, float* __restrict__ dis,
                             int* __restrict__ row_ptr_end, int n, int E) {
  int i = blockIdx.x * blockDim.x + threadIdx.x;
  if (i == 0) *row_ptr_end = E;
  if (i < n) {
    cursor[i] = row_ptr[i];
    dis[i] = rsqrtf((float)cnt[i] + 1.0f);
  }
}

__global__ void k_scatter(const int* __restrict__ src, const int* __restrict__ dst, int E,
                          int* __restrict__ cursor, int* __restrict__ col) {
  int i = blockIdx.x * blockDim.x + threadIdx.x;
  if (i < E) {
    int d = dst[i];
    int pos = atomicAdd(&cursor[d], 1);
    col[pos] = src[i];
  }
}

// ---------------------------------------------------------------- weight prep
// W[K][O] fp32 -> Wt_hi[O][K], Wt_lo[O][K] bf16 (transposed + hi/lo split)

struct WSpec { const float* W; ushort* hi; ushort* lo; int K; int O; };
struct WPack { WSpec s[9]; };

__global__ void k_wprep(WPack p) {
  const WSpec w = p.s[blockIdx.y];
  const int total = w.K * w.O;
  for (int i = blockIdx.x * 256 + threadIdx.x; i < total; i += gridDim.x * 256) {
    const int o = i / w.K;
    const int k = i - o * w.K;
    const float v = w.W[(size_t)k * w.O + o];
    const ushort h = f2bf_rne(v);
    w.hi[i] = h;
    w.lo[i] = f2bf_rne(v - bf2f(h));
  }
}

// ---------------------------------------------------------------- prep pass
// out = pack_bf16( ACT ? lrelu(X*sc + sh) : X ); optional lo plane (SPLIT).

template <bool INBF, bool ACT, bool SPLIT, int H>
__global__ void k_prep(const void* __restrict__ Xv, const float* __restrict__ ss,
                       ushort* __restrict__ out, size_t planeOff, int total) {
  const int i8 = (blockIdx.x * 256 + threadIdx.x) * 8;
  if (i8 >= total) return;
  const int c0 = i8 & (H - 1);
  float f[8];
  if (INBF) {
    const ushort8v u = *reinterpret_cast<const ushort8v*>((const ushort*)Xv + i8);
#pragma unroll
    for (int j = 0; j < 8; ++j) f[j] = bf2f(u[j]);
  } else {
    const float* X = (const float*)Xv;
    const float4 a = *reinterpret_cast<const float4*>(&X[i8]);
    const float4 b = *reinterpret_cast<const float4*>(&X[i8 + 4]);
    f[0] = a.x; f[1] = a.y; f[2] = a.z; f[3] = a.w;
    f[4] = b.x; f[5] = b.y; f[6] = b.z; f[7] = b.w;
  }
  if (ACT) {
    const float4 sa = *reinterpret_cast<const float4*>(&ss[c0]);
    const float4 sb = *reinterpret_cast<const float4*>(&ss[c0 + 4]);
    const float4 ha = *reinterpret_cast<const float4*>(&ss[H + c0]);
    const float4 hb = *reinterpret_cast<const float4*>(&ss[H + c0 + 4]);
    const float sc[8] = {sa.x, sa.y, sa.z, sa.w, sb.x, sb.y, sb.z, sb.w};
    const float sh[8] = {ha.x, ha.y, ha.z, ha.w, hb.x, hb.y, hb.z, hb.w};
#pragma unroll
    for (int j = 0; j < 8; ++j) {
      float x = f[j] * sc[j] + sh[j];
      f[j] = x > 0.f ? x : 0.01f * x;
    }
  }
  ushort8v hi;
#pragma unroll
  for (int j = 0; j < 8; ++j) hi[j] = f2bf_rne(f[j]);
  *reinterpret_cast<ushort8v*>(&out[i8]) = hi;
  if (SPLIT) {
    ushort8v lo;
#pragma unroll
    for (int j = 0; j < 8; ++j) lo[j] = f2bf_rne(f[j] - bf2f(hi[j]));
    *reinterpret_cast<ushort8v*>(&out[planeOff + i8]) = lo;
  }
}

// ---------------------------------------------------------------- MFMA GEMM (no LDS)
// C[N,O] = A[N,K](bf16) @ W[K,O] (+bias). W pre-split transposed bf16 hi+lo
// (2 MFMAs per fragment pair; +1 with A lo-plane when ASPLIT). A and B
// fragments load straight from L2 each k-step; no barriers in main loop.
// STATS: fused column sum/sumsq (of biased output, rows<N) into `sums`.

template <int K, int O, bool ASPLIT, bool STATS, bool OUTBF, bool BIAS>
__launch_bounds__(256)
__global__ void k_gemm2(const ushort* __restrict__ A, const ushort* __restrict__ Whi,
                        const ushort* __restrict__ Wlo, const float* __restrict__ bias,
                        void* __restrict__ Cout, float* __restrict__ sums, int N) {
  constexpr int BN = (O >= 128) ? 128 : O;
  constexpr int KS = K / 32;
  constexpr int WC = (BN == 128) ? 2 : 1;
  constexpr int WR = 4 / WC;
  constexpr int MF = (128 / WR) / 16;
  constexpr int NF = 4;

  const int bm = blockIdx.x * 128;
  const int bo = blockIdx.y * BN;
  const int t = threadIdx.x;
  const int w = t >> 6, l = t & 63;
  const int wr = w / WC, wc = w - wr * WC;
  const int r0 = wr * (MF * 16);
  const int c0 = wc * 64;
  const int lr = l & 15;
  const int lk = (l >> 4) * 8;
  const size_t loOff = (size_t)N * K;

  f32x4 acc[MF][NF];
  const f32x4 zero4 = {0.f, 0.f, 0.f, 0.f};
#pragma unroll
  for (int mf = 0; mf < MF; ++mf)
#pragma unroll
    for (int nf = 0; nf < NF; ++nf) acc[mf][nf] = zero4;

  int arow[MF];
#pragma unroll
  for (int mf = 0; mf < MF; ++mf) {
    const int r = bm + r0 + mf * 16 + lr;
    arow[mf] = r < N ? r : N - 1;
  }

#pragma unroll 2
  for (int ks = 0; ks < KS; ++ks) {
    short8 bh[NF], bl[NF];
#pragma unroll
    for (int nf = 0; nf < NF; ++nf) {
      const size_t boff = (size_t)(bo + c0 + nf * 16 + lr) * K + ks * 32 + lk;
      bh[nf] = *reinterpret_cast<const short8*>(&Whi[boff]);
      bl[nf] = *reinterpret_cast<const short8*>(&Wlo[boff]);
    }
    short8 ah[MF], al[MF];
#pragma unroll
    for (int mf = 0; mf < MF; ++mf) {
      const size_t aoff = (size_t)arow[mf] * K + ks * 32 + lk;
      ah[mf] = *reinterpret_cast<const short8*>(&A[aoff]);
      if (ASPLIT) al[mf] = *reinterpret_cast<const short8*>(&A[loOff + aoff]);
    }
#pragma unroll
    for (int mf = 0; mf < MF; ++mf) {
#pragma unroll
      for (int nf = 0; nf < NF; ++nf) {
        acc[mf][nf] = __builtin_amdgcn_mfma_f32_16x16x32_bf16(ah[mf], bh[nf], acc[mf][nf], 0, 0, 0);
        acc[mf][nf] = __builtin_amdgcn_mfma_f32_16x16x32_bf16(ah[mf], bl[nf], acc[mf][nf], 0, 0, 0);
        if (ASPLIT)
          acc[mf][nf] = __builtin_amdgcn_mfma_f32_16x16x32_bf16(al[mf], bh[nf], acc[mf][nf], 0, 0, 0);
      }
    }
  }

  // epilogue: C[row = bm+r0+mf*16+(l>>4)*4+rg][col = bo+c0+nf*16+lr]
  float s[NF], q[NF];
#pragma unroll
  for (int nf = 0; nf < NF; ++nf) { s[nf] = 0.f; q[nf] = 0.f; }
#pragma unroll
  for (int mf = 0; mf < MF; ++mf) {
    const int gr0 = bm + r0 + mf * 16 + (l >> 4) * 4;
#pragma unroll
    for (int nf = 0; nf < NF; ++nf) {
      const int gc = bo + c0 + nf * 16 + lr;
      float bval = 0.f;
      if (BIAS) bval = bias[gc];
#pragma unroll
      for (int rg = 0; rg < 4; ++rg) {
        const int row = gr0 + rg;
        if (row < N) {
          const float v = acc[mf][nf][rg] + bval;
          if (OUTBF)
            ((ushort*)Cout)[(size_t)row * O + gc] = f2bf_rne(v);
          else
            ((float*)Cout)[(size_t)row * O + gc] = v;
          if (STATS) { s[nf] += v; q[nf] += v * v; }
        }
      }
    }
  }

  if (STATS) {
    __shared__ float sred[4][NF][16][2];
#pragma unroll
    for (int nf = 0; nf < NF; ++nf) {
      s[nf] += __shfl_xor(s[nf], 16);
      s[nf] += __shfl_xor(s[nf], 32);
      q[nf] += __shfl_xor(q[nf], 16);
      q[nf] += __shfl_xor(q[nf], 32);
    }
    if (l < 16) {
#pragma unroll
      for (int nf = 0; nf < NF; ++nf) {
        sred[w][nf][l][0] = s[nf];
        sred[w][nf][l][1] = q[nf];
      }
    }
    __syncthreads();
    if (t < BN) {
      const int wcsel = (WC == 2) ? (t >> 6) : 0;
      const int nfi = (t >> 4) & 3;
      const int lri = t & 15;
      float S = 0.f, Q = 0.f;
#pragma unroll
      for (int ww = 0; ww < WR; ++ww) {
        const int w2 = ww * WC + wcsel;
        S += sred[w2][nfi][lri][0];
        Q += sred[w2][nfi][lri][1];
      }
      atomicAdd(&sums[bo + t], S);
      atomicAdd(&sums[O + bo + t], Q);
    }
  }
}

// ---------------------------------------------------------------- BN finalize

__global__ void k_bnfin(const float* __restrict__ sums, const float* __restrict__ g,
                        const float* __restrict__ b, float* __restrict__ ss, int H, float invN) {
  const int c = threadIdx.x;
  if (c < H) {
    const float mean = sums[c] * invN;
    float var = sums[H + c] * invN - mean * mean;
    var = var < 0.f ? 0.f : var;
    const float sc = g[c] * rsqrtf(var + 1e-5f);
    ss[c] = sc;
    ss[H + c] = b[c] - mean * sc;
  }
}

// ---------------------------------------------------------------- bf16 column stats

template <int H>
__launch_bounds__(256)
__global__ void k_colstats_bf(const ushort* __restrict__ X, int n, float* __restrict__ sums) {
  constexpr int G = H / 8;
  constexpr int NS = 256 / G;
  const int t = threadIdx.x;
  const int cg = t % G;
  const int sub = t / G;
  const int r0 = blockIdx.x * 256;
  const int rend = (r0 + 256 < n) ? r0 + 256 : n;
  float s[8], q[8];
#pragma unroll
  for (int j = 0; j < 8; ++j) { s[j] = 0.f; q[j] = 0.f; }
  for (int r = r0 + sub; r < rend; r += NS) {
    const ushort8v u = *reinterpret_cast<const ushort8v*>(&X[(size_t)r * H + cg * 8]);
#pragma unroll
    for (int j = 0; j < 8; ++j) {
      const float f = bf2f(u[j]);
      s[j] += f;
      q[j] += f * f;
    }
  }
  __shared__ float red[256][16];
#pragma unroll
  for (int j = 0; j < 8; ++j) { red[t][j] = s[j]; red[t][8 + j] = q[j]; }
  __syncthreads();
  if (sub == 0) {
#pragma unroll
    for (int k = 1; k < NS; ++k) {
      const int u2 = cg + k * G;
#pragma unroll
      for (int j = 0; j < 8; ++j) { s[j] += red[u2][j]; q[j] += red[u2][8 + j]; }
    }
#pragma unroll
    for (int j = 0; j < 8; ++j) {
      atomicAdd(&sums[cg * 8 + j], s[j]);
      atomicAdd(&sums[H + cg * 8 + j], q[j]);
    }
  }
}

// ---------------------------------------------------------------- GCN aggregation
// out[d] = sum_{e:(s->d)} Hin[s]*dis[s]*dis[d] + Hin[d]*dis[d]^2 + bias, bf16 out.
// Wave split into 2 half-waves, each processes its own edges (32 lanes cover the
// whole H-row: 16B/lane at H=256), 4-deep batching per half -> 8 chains in flight.
// COMBINE: out = ((xin*sc+sh) + agg) * 2^-0.5 + xin   (residual fused).

template <int H, bool COMBINE>
__launch_bounds__(256)
__global__ void k_agg2(const ushort* __restrict__ Hin, const int* __restrict__ row_ptr,
                       const int* __restrict__ col, const float* __restrict__ dis,
                       const float* __restrict__ bias, const float* __restrict__ xin,
                       const float* __restrict__ ss, ushort* __restrict__ out, int n) {
  constexpr int VC = H / 32;  // elems per lane (8 or 4)
  const int t = threadIdx.x;
  const int lane = t & 63;
  const int node = blockIdx.x * 4 + (t >> 6);
  if (node >= n) return;
  const int half = lane >> 5;
  const int sl = lane & 31;
  const int c0 = sl * VC;
  const int beg = row_ptr[node];
  const int end = row_ptr[node + 1];
  const float dd = dis[node];

  float acc[VC];
#pragma unroll
  for (int j = 0; j < VC; ++j) acc[j] = 0.f;

  for (int e = beg + half; e < end; e += 8) {
    int s4[4];
    float w4[4];
#pragma unroll
    for (int i = 0; i < 4; ++i) {
      const int idx = e + 2 * i;
      const bool valid = idx < end;
      s4[i] = col[valid ? idx : beg];
      w4[i] = valid ? dd : 0.f;
    }
#pragma unroll
    for (int i = 0; i < 4; ++i) w4[i] *= dis[s4[i]];
#pragma unroll
    for (int i = 0; i < 4; ++i) {
      if constexpr (VC == 8) {
        const ushort8v u = *reinterpret_cast<const ushort8v*>(&Hin[(size_t)s4[i] * H + c0]);
#pragma unroll
        for (int j = 0; j < 8; ++j) acc[j] += bf2f(u[j]) * w4[i];
      } else {
        const ushort4 u = *reinterpret_cast<const ushort4*>(&Hin[(size_t)s4[i] * H + c0]);
        acc[0] += bf2f(u.x) * w4[i];
        acc[1] += bf2f(u.y) * w4[i];
        acc[2] += bf2f(u.z) * w4[i];
        acc[3] += bf2f(u.w) * w4[i];
      }
    }
  }

#pragma unroll
  for (int j = 0; j < VC; ++j) acc[j] += __shfl_xor(acc[j], 32);

  if (half == 0) {
    const float sw = dd * dd;
    float r[VC];
    if constexpr (VC == 8) {
      const ushort8v u = *reinterpret_cast<const ushort8v*>(&Hin[(size_t)node * H + c0]);
#pragma unroll
      for (int j = 0; j < 8; ++j) r[j] = acc[j] + bf2f(u[j]) * sw + bias[c0 + j];
    } else {
      const ushort4 u = *reinterpret_cast<const ushort4*>(&Hin[(size_t)node * H + c0]);
      r[0] = acc[0] + bf2f(u.x) * sw + bias[c0 + 0];
      r[1] = acc[1] + bf2f(u.y) * sw + bias[c0 + 1];
      r[2] = acc[2] + bf2f(u.z) * sw + bias[c0 + 2];
      r[3] = acc[3] + bf2f(u.w) * sw + bias[c0 + 3];
    }
    if (COMBINE) {
      const float cinv = 0.70710678118654752f;
#pragma unroll
      for (int j4 = 0; j4 < VC; j4 += 4) {
        const float4 x = *reinterpret_cast<const float4*>(&xin[(size_t)node * H + c0 + j4]);
        const float4 sc = *reinterpret_cast<const float4*>(&ss[c0 + j4]);
        const float4 sh = *reinterpret_cast<const float4*>(&ss[H + c0 + j4]);
        r[j4 + 0] = (x.x * sc.x + sh.x + r[j4 + 0]) * cinv + x.x;
        r[j4 + 1] = (x.y * sc.y + sh.y + r[j4 + 1]) * cinv + x.y;
        r[j4 + 2] = (x.z * sc.z + sh.z + r[j4 + 2]) * cinv + x.z;
        r[j4 + 3] = (x.w * sc.w + sh.w + r[j4 + 3]) * cinv + x.w;
      }
    }
    if constexpr (VC == 8) {
      ushort8v o;
#pragma unroll
      for (int j = 0; j < 8; ++j) o[j] = f2bf_rne(r[j]);
      *reinterpret_cast<ushort8v*>(&out[(size_t)node * H + c0]) = o;
    } else {
      ushort4 o;
      o.x = f2bf_rne(r[0]); o.y = f2bf_rne(r[1]);
      o.z = f2bf_rne(r[2]); o.w = f2bf_rne(r[3]);
      *reinterpret_cast<ushort4*>(&out[(size_t)node * H + c0]) = o;
    }
  }
}

// ---------------------------------------------------------------- launch

extern "C" void kernel_launch(void* const* d_in, const int* in_sizes, int n_in,
                              void* d_out, int out_size, void* d_ws, size_t ws_size,
                              hipStream_t stream) {
  const int N = in_sizes[0] / 128;
  const int E = in_sizes[1] / 2;

  const float* x_vert = (const float*)d_in[0];
  const int* src = (const int*)d_in[1];
  const int* dst = src + E;
  const float* g1_lin_W = (const float*)d_in[2];
  const float* g1_lin_b = (const float*)d_in[3];
  const float* g1_c1_W = (const float*)d_in[4];
  const float* g1_c1_b = (const float*)d_in[5];
  const float* g1_c2_W = (const float*)d_in[6];
  const float* g1_c2_b = (const float*)d_in[7];
  const float* g1_n1_g = (const float*)d_in[8];
  const float* g1_n1_b = (const float*)d_in[9];
  const float* g1_n2_g = (const float*)d_in[10];
  const float* g1_n2_b = (const float*)d_in[11];
  const float* g2_lin_W = (const float*)d_in[12];
  const float* g2_lin_b = (const float*)d_in[13];
  const float* g2_c1_W = (const float*)d_in[14];
  const float* g2_c1_b = (const float*)d_in[15];
  const float* g2_c2_W = (const float*)d_in[16];
  const float* g2_c2_b = (const float*)d_in[17];
  const float* g2_n1_g = (const float*)d_in[18];
  const float* g2_n1_b = (const float*)d_in[19];
  const float* g2_n2_g = (const float*)d_in[20];
  const float* g2_n2_b = (const float*)d_in[21];
  const float* out_W = (const float*)d_in[22];
  const float* out_b = (const float*)d_in[23];
  const float* n1_g = (const float*)d_in[24];
  const float* n1_b = (const float*)d_in[25];
  const float* l1_W = (const float*)d_in[26];
  const float* l1_b = (const float*)d_in[27];
  const float* n2_g = (const float*)d_in[28];
  const float* n2_b = (const float*)d_in[29];
  const float* l2_W = (const float*)d_in[30];
  const float* l2_b = (const float*)d_in[31];

  float* out = (float*)d_out;

  // ---- workspace carve-up
  size_t off = 0;
  auto alloc = [&](size_t bytes) -> void* {
    void* p = (char*)d_ws + off;
    off += (bytes + 255) & ~(size_t)255;
    return p;
  };
  float* B1 = (float*)alloc((size_t)N * 256 * 4);    // x_in block1 (fp32, residual src)
  float* B2 = (float*)alloc((size_t)N * 128 * 4);    // x_in block2 (fp32, residual src)
  ushort* sA = (ushort*)alloc((size_t)N * 256 * 2);  // rotating bf16 slot A
  ushort* sB = (ushort*)alloc((size_t)N * 256 * 2);  // rotating bf16 slot B
  ushort* Xb = (ushort*)alloc((size_t)N * 128 * 2);  // packed x_vert
  int* cnt = (int*)alloc((size_t)N * 4);
  int* row_ptr = (int*)alloc((size_t)(N + 1) * 4);
  int* cursor = (int*)alloc((size_t)N * 4);
  int* col = (int*)alloc((size_t)E * 4);
  int* part = (int*)alloc(1024 * 4);
  float* dis = (float*)alloc((size_t)N * 4);
  float* sums = (float*)alloc(6 * 512 * 4);
  float* ssv = (float*)alloc(6 * 512 * 4);

  const int wk[9] = {128, 256, 256, 256, 128, 128, 128, 128, 64};
  const int wo[9] = {256, 256, 256, 128, 128, 128, 128, 64, 64};
  const float* wsrc[9] = {g1_lin_W, g1_c1_W, g1_c2_W, g2_lin_W, g2_c1_W,
                          g2_c2_W, out_W, l1_W, l2_W};
  ushort* whi[9];
  ushort* wlo[9];
  for (int i = 0; i < 9; ++i) {
    whi[i] = (ushort*)alloc((size_t)wk[i] * wo[i] * 2);
    wlo[i] = (ushort*)alloc((size_t)wk[i] * wo[i] * 2);
  }
  (void)ws_size;
  (void)n_in;
  (void)out_size;

  const int NB = IDIV(N, 256);
  const int GM = IDIV(N, 128);
  const float invN = 1.0f / (float)N;
  float* ss0 = ssv + 0 * 512;
  float* ss1 = ssv + 1 * 512;
  float* ss2 = ssv + 2 * 512;
  float* ss3 = ssv + 3 * 512;
  float* ss4 = ssv + 4 * 512;
  float* ss5 = ssv + 5 * 512;

  // ---- CSR build + weight prep + input pack
  k_zero_i32<<<NB, 256, 0, stream>>>(cnt, N);
  k_zero_f32<<<IDIV(6 * 512, 256), 256, 0, stream>>>(sums, 6 * 512);
  {
    WPack p;
    for (int i = 0; i < 9; ++i) p.s[i] = WSpec{wsrc[i], whi[i], wlo[i], wk[i], wo[i]};
    k_wprep<<<dim3(64, 9), 256, 0, stream>>>(p);
  }
  k_prep<false, false, false, 128><<<IDIV(N * 128, 2048), 256, 0, stream>>>(x_vert, nullptr, Xb, 0, N * 128);
  k_count<<<IDIV(E, 256), 256, 0, stream>>>(dst, E, cnt);
  k_scan_partial<<<NB, 256, 0, stream>>>(cnt, N, part);
  k_scan_offsets<<<1, 256, 0, stream>>>(part, NB);
  k_scan_final<<<NB, 256, 0, stream>>>(cnt, N, part, row_ptr);
  k_cursor_dis<<<NB, 256, 0, stream>>>(row_ptr, cnt, cursor, dis, row_ptr + N, N, E);
  k_scatter<<<IDIV(E, 256), 256, 0, stream>>>(src, dst, E, cursor, col);

  // ================= block 1 (in 128, hid 256) =================
  k_gemm2<128, 256, false, true, false, true>
      <<<dim3(GM, 2), 256, 0, stream>>>(Xb, whi[0], wlo[0], g1_lin_b, B1, sums + 0 * 512, N);
  k_bnfin<<<1, 256, 0, stream>>>(sums + 0 * 512, g1_n1_g, g1_n1_b, ss0, 256, invN);
  k_prep<false, true, false, 256><<<IDIV(N * 256, 2048), 256, 0, stream>>>(B1, ss0, sA, 0, N * 256);
  k_gemm2<256, 256, false, false, true, false>
      <<<dim3(GM, 2), 256, 0, stream>>>(sA, whi[1], wlo[1], nullptr, sB, nullptr, N);
  k_agg2<256, false><<<IDIV(N, 4), 256, 0, stream>>>(sB, row_ptr, col, dis, g1_c1_b, nullptr, nullptr, sA, N);
  k_colstats_bf<256><<<NB, 256, 0, stream>>>(sA, N, sums + 1 * 512);
  k_bnfin<<<1, 256, 0, stream>>>(sums + 1 * 512, g1_n2_g, g1_n2_b, ss1, 256, invN);
  k_prep<true, true, false, 256><<<IDIV(N * 256, 2048), 256, 0, stream>>>(sA, ss1, sB, 0, N * 256);
  k_gemm2<256, 256, false, false, true, false>
      <<<dim3(GM, 2), 256, 0, stream>>>(sB, whi[2], wlo[2], nullptr, sA, nullptr, N);
  k_agg2<256, true><<<IDIV(N, 4), 256, 0, stream>>>(sA, row_ptr, col, dis, g1_c2_b, B1, ss0, sB, N);

  // ================= block 2 (in 256, hid 128) =================
  k_gemm2<256, 128, false, true, false, true>
      <<<dim3(GM, 1), 256, 0, stream>>>(sB, whi[3], wlo[3], g2_lin_b, B2, sums + 2 * 512, N);
  k_bnfin<<<1, 256, 0, stream>>>(sums + 2 * 512, g2_n1_g, g2_n1_b, ss2, 128, invN);
  k_prep<false, true, false, 128><<<IDIV(N * 128, 2048), 256, 0, stream>>>(B2, ss2, sA, 0, N * 128);
  k_gemm2<128, 128, false, false, true, false>
      <<<dim3(GM, 1), 256, 0, stream>>>(sA, whi[4], wlo[4], nullptr, sB, nullptr, N);
  k_agg2<128, false><<<IDIV(N, 4), 256, 0, stream>>>(sB, row_ptr, col, dis, g2_c1_b, nullptr, nullptr, sA, N);
  k_colstats_bf<128><<<NB, 256, 0, stream>>>(sA, N, sums + 3 * 512);
  k_bnfin<<<1, 256, 0, stream>>>(sums + 3 * 512, g2_n2_g, g2_n2_b, ss3, 128, invN);
  k_prep<true, true, false, 128><<<IDIV(N * 128, 2048), 256, 0, stream>>>(sA, ss3, sB, 0, N * 128);
  k_gemm2<128, 128, false, false, true, false>
      <<<dim3(GM, 1), 256, 0, stream>>>(sB, whi[5], wlo[5], nullptr, sA, nullptr, N);
  k_agg2<128, true><<<IDIV(N, 4), 256, 0, stream>>>(sA, row_ptr, col, dis, g2_c2_b, B2, ss2, sB, N);

  // ================= head =================
  k_gemm2<128, 128, false, true, true, true>
      <<<dim3(GM, 1), 256, 0, stream>>>(sB, whi[6], wlo[6], out_b, sA, sums + 4 * 512, N);
  k_bnfin<<<1, 256, 0, stream>>>(sums + 4 * 512, n1_g, n1_b, ss4, 128, invN);
  k_prep<true, true, true, 128><<<IDIV(N * 128, 2048), 256, 0, stream>>>(sA, ss4, sB, (size_t)N * 128, N * 128);
  k_gemm2<128, 64, true, true, true, true>
      <<<dim3(GM, 1), 256, 0, stream>>>(sB, whi[7], wlo[7], l1_b, sA, sums + 5 * 512, N);
  k_bnfin<<<1, 256, 0, stream>>>(sums + 5 * 512, n2_g, n2_b, ss5, 64, invN);
  k_prep<true, true, true, 64><<<IDIV(N * 64, 2048), 256, 0, stream>>>(sA, ss5, sB, (size_t)N * 64, N * 64);
  k_gemm2<64, 64, true, false, false, true>
      <<<dim3(GM, 1), 256, 0, stream>>>(sB, whi[8], wlo[8], l2_b, out, nullptr, N);
}